// Round 6
// baseline (462.531 us; speedup 1.0000x reference)
//
#include <hip/hip_runtime.h>
#include <cstdint>
#include <cstddef>

// ---------------- problem constants ----------------
#define NEXP   32          // routed experts
#define TOPK   4
#define HD     1024        // hidden
#define ID     512         // intermediate
#define TT     4096        // tokens (B*S)
#define CAP    1024        // capacity per routed expert
#define SHARED_BASE (NEXP*CAP)        // 32768 : slot base of shared-expert rows
#define NSLOT  (NEXP*CAP + TT)        // 36864 total slot rows
#define GRIDY  80          // >= 4 * ceil(maxtiles(144)/8) = 72

#define KSPLIT 16          // router split-K
#define KCH    64          // K per logits block
#define KSUB   32          // LDS sub-chunk

typedef __attribute__((ext_vector_type(4))) float f32x4;
typedef __bf16 bf16x8 __attribute__((ext_vector_type(8)));

__device__ __forceinline__ unsigned short f2bf(float f) {
    union { float f; unsigned int u; } v; v.f = f;
    unsigned int u = v.u;
    u = (u + 0x7FFFu + ((u >> 16) & 1u)) >> 16;   // RNE
    return (unsigned short)u;
}
__device__ __forceinline__ float bf2f(unsigned short s) {
    union { unsigned int u; float f; } v; v.u = ((unsigned int)s) << 16;
    return v.f;
}

#define GLOAD_LDS16(g, l)                                                     \
    __builtin_amdgcn_global_load_lds(                                         \
        (__attribute__((address_space(1))) void*)(g),                         \
        (__attribute__((address_space(3))) void*)(l), 16, 0, 0)

// ---------------- fp32 [K][N] -> bf16 [N][K] transpose ---------------------
// z < NEXP: expert z of src; z == NEXP: shared-expert srcS (appended slot).
__global__ void k_transpose_bf16(const float* __restrict__ src,
                                 const float* __restrict__ srcS,
                                 unsigned short* __restrict__ dst,
                                 int K, int N) {
    __shared__ float ld[64][65];      // +1 pad: conflict-free transpose
    const size_t esz = (size_t)K * N;
    const int z = blockIdx.z;
    const float* s = (z < NEXP) ? src + (size_t)z * esz : srcS;
    dst += (size_t)z * esz;
    const int n0 = blockIdx.x * 64, k0 = blockIdx.y * 64;
    const int tid = threadIdx.x;
    const int c4 = (tid & 15) * 4;
    const int rbase = tid >> 4;        // 0..15
#pragma unroll
    for (int p = 0; p < 4; p++) {
        int row = rbase + p * 16;
        float4 v = *(const float4*)(s + (size_t)(k0 + row) * N + n0 + c4);
        ld[row][c4 + 0] = v.x; ld[row][c4 + 1] = v.y;
        ld[row][c4 + 2] = v.z; ld[row][c4 + 3] = v.w;
    }
    __syncthreads();
    const int n  = tid >> 2;           // 0..63
    const int ks = (tid & 3) * 16;     // k segment
    unsigned short tmp[16];
#pragma unroll
    for (int i = 0; i < 16; i++) tmp[i] = f2bf(ld[ks + i][n]);
    uint4 a, b;
    a.x = tmp[0] | (tmp[1] << 16);  a.y = tmp[2] | (tmp[3] << 16);
    a.z = tmp[4] | (tmp[5] << 16);  a.w = tmp[6] | (tmp[7] << 16);
    b.x = tmp[8] | (tmp[9] << 16);  b.y = tmp[10] | (tmp[11] << 16);
    b.z = tmp[12] | (tmp[13] << 16); b.w = tmp[14] | (tmp[15] << 16);
    unsigned short* op = dst + (size_t)(n0 + n) * K + k0 + ks;
    *(uint4*)op = a;
    *(uint4*)(op + 8) = b;
}

// ---------------- router part 1: fp32 logits + fused x->bf16 convert ------
__global__ __launch_bounds__(256)
void k_logits(const float* __restrict__ x, const float* __restrict__ gw,
              float* __restrict__ part, unsigned short* __restrict__ xb) {
    __shared__ float xsT[KSUB][260];
    __shared__ float gsT[KSUB][36];
    const int tid = threadIdx.x;
    const int lane = tid & 63, wv = tid >> 6;
    const int tg = lane >> 2, eg = lane & 3;
    const int t0 = blockIdx.x * 256;
    const int kbase = blockIdx.y * KCH;
    const int tbase = wv * 64 + tg * 4;
    const int ebase = eg * 8;

    float acc[4][8];
#pragma unroll
    for (int j = 0; j < 4; j++)
#pragma unroll
        for (int i = 0; i < 8; i++) acc[j][i] = 0.f;

    for (int ks = 0; ks < KCH; ks += KSUB) {
        const int k0 = kbase + ks;
        if (ks > 0) __syncthreads();
#pragma unroll
        for (int p = 0; p < 8; p++) {
            int vid = p * 256 + tid;
            int t = vid >> 3, kq = (vid & 7) * 4;
            float4 v = *(const float4*)(x + (size_t)(t0 + t) * HD + k0 + kq);
            xsT[kq + 0][t] = v.x; xsT[kq + 1][t] = v.y;
            xsT[kq + 2][t] = v.z; xsT[kq + 3][t] = v.w;
            ushort4 o;
            o.x = f2bf(v.x); o.y = f2bf(v.y); o.z = f2bf(v.z); o.w = f2bf(v.w);
            *(ushort4*)(xb + (size_t)(t0 + t) * HD + k0 + kq) = o;
        }
#pragma unroll
        for (int p = 0; p < 4; p++) {
            int vid = p * 256 + tid;
            int e = vid >> 5, k = vid & 31;
            gsT[k][e] = gw[(size_t)e * HD + k0 + k];
        }
        __syncthreads();
#pragma unroll 4
        for (int k = 0; k < KSUB; k++) {
            float4 xv = *(const float4*)&xsT[k][tbase];
            float4 g0 = *(const float4*)&gsT[k][ebase];
            float4 g1 = *(const float4*)&gsT[k][ebase + 4];
            float xa[4] = {xv.x, xv.y, xv.z, xv.w};
#pragma unroll
            for (int j = 0; j < 4; j++) {
                acc[j][0] += xa[j] * g0.x; acc[j][1] += xa[j] * g0.y;
                acc[j][2] += xa[j] * g0.z; acc[j][3] += xa[j] * g0.w;
                acc[j][4] += xa[j] * g1.x; acc[j][5] += xa[j] * g1.y;
                acc[j][6] += xa[j] * g1.z; acc[j][7] += xa[j] * g1.w;
            }
        }
    }
    const size_t base = ((size_t)blockIdx.y * TT + (t0 + tbase)) * 32 + ebase;
#pragma unroll
    for (int j = 0; j < 4; j++) {
        float4 w0, w1;
        w0.x = acc[j][0]; w0.y = acc[j][1]; w0.z = acc[j][2]; w0.w = acc[j][3];
        w1.x = acc[j][4]; w1.y = acc[j][5]; w1.z = acc[j][6]; w1.w = acc[j][7];
        *(float4*)(part + base + (size_t)j * 32) = w0;
        *(float4*)(part + base + (size_t)j * 32 + 4) = w1;
    }
}

// ---------------- router part 2: reduce partials, top-4 (NO atomics) ------
__global__ __launch_bounds__(256)
void k_topk(const float* __restrict__ part,
            int* __restrict__ choice, float* __restrict__ cw,
            int* __restrict__ tok, float* __restrict__ wgt) {
    const int lane = threadIdx.x & 63, wv = threadIdx.x >> 6;
    const int t = blockIdx.x * 4 + wv;
    const int e = lane & 31;
    const int sbase = (lane >> 5) * 8;
    float v = 0.f;
#pragma unroll
    for (int s = 0; s < 8; s++)
        v += part[((size_t)(sbase + s) * TT + t) * 32 + e];
    v += __shfl_xor(v, 32);
    float sc = (lane < 32) ? v : -INFINITY;

    float lv[TOPK]; int le[TOPK];
#pragma unroll
    for (int r = 0; r < TOPK; r++) {
        float m = sc;
#pragma unroll
        for (int d = 1; d < 64; d <<= 1) m = fmaxf(m, __shfl_xor(m, d));
        unsigned long long ball = __ballot(sc == m);
        int widx = __ffsll(ball) - 1;       // lowest lane on tie = jax top_k
        lv[r] = m; le[r] = widx;
        if (lane == widx) sc = -INFINITY;
    }
    if (lane == 0) {
        float wv4[TOPK], wsum = 0.f;
#pragma unroll
        for (int r = 0; r < TOPK; r++) { wv4[r] = __expf(lv[r] - lv[0]); wsum += wv4[r]; }
#pragma unroll
        for (int r = 0; r < TOPK; r++) {
            choice[t * TOPK + r] = le[r];
            cw[t * TOPK + r] = wv4[r] / wsum;
        }
        tok[SHARED_BASE + t] = t;            // shared-expert identity slot
        wgt[SHARED_BASE + t] = 1.0f;
    }
}

// ---------------- slot assignment: deterministic ballot-scan, 1 blk/expert -
__global__ __launch_bounds__(1024)
void k_assign(const int* __restrict__ choice, const float* __restrict__ cw,
              int* __restrict__ cnt, int* __restrict__ tok,
              float* __restrict__ wgt, int* __restrict__ smap) {
    const int e = blockIdx.x;
    const int tid = threadIdx.x, lane = tid & 63, wv = tid >> 6;
    __shared__ int wtot[16];
    int running = 0;
    for (int it = 0; it < (TT * TOPK) / 1024; it++) {
        const int i = it * 1024 + tid;
        const bool match = (choice[i] == e);
        unsigned long long ball = __ballot(match);
        int wt = __popcll(ball);
        int wpre = __popcll(ball & ((1ull << lane) - 1ull));
        if (lane == 0) wtot[wv] = wt;
        __syncthreads();
        int woff = 0, tot = 0;
#pragma unroll
        for (int w = 0; w < 16; w++) { int c = wtot[w]; tot += c; if (w < wv) woff += c; }
        int pos = running + woff + wpre;
        running += tot;
        __syncthreads();
        if (match) {
            if (pos < CAP) {
                int slot = e * CAP + pos;
                tok[slot] = i >> 2;          // token id
                wgt[slot] = cw[i];
                smap[i] = slot;
            } else {
                smap[i] = -1;                // overflow dropped (P ~ 0)
            }
        }
    }
    if (tid == 0) cnt[e] = min(running, CAP);
}

// ---------------- grouped GEMM: 256x256 tile, 8 waves, 8-phase schedule ---
// T3+T4 (+T5) port of the m201 template to the grouped MoE GEMM:
//   LDS ring of 4 32-K chunks (128 KB), prefetch lead 3.
//   Per chunk, 2 phases: {ds_read subtile + issue 2 global_load_lds ->
//   s_barrier -> lgkmcnt(0) -> setprio(1) 16 MFMA setprio(0) -> s_barrier}.
//   Counted vmcnt(8) ONCE per chunk (4 loads/chunk/wave, 2 chunks in
//   flight after the wait) -> loads span barriers, never drained to 0 in
//   the main loop. Peeled tail: vmcnt(4), vmcnt(0), none.
//   Ring safety: prefetch of chunk t+3 writes buf (t+3)&3 == (t-1)&3,
//   whose reads were drained by chunk t-1's lgkmcnt(0)+barrier.
// SILU tiles pair gate/up rows: a 256-row B tile covers 128 OUTPUT columns
// => GEMM1 (ID=512) NT=4; GEMM2 (HD=1024) 256 cols/tile, NT=4.
// In-kernel tile table (33-lane prefix scan over cnt) + XCD chunking (T1).
// LDS k-seg XOR swizzle (slot s of row r holds seg s^((r>>1)&3)): 0 conflicts.
#define GEMM_ITER(T, PF, W)                                                    \
{                                                                              \
    const unsigned short* Ar = &As[(T) & 3][0];                                \
    const unsigned short* Br = &Bs[(T) & 3][0];                                \
    const int kn = ((T) + 3) * 32;                                             \
    bf16x8 af[8], bf[4];                                                       \
    _Pragma("unroll")                                                          \
    for (int i = 0; i < 4; i++) {                                              \
        af[i] = *(const bf16x8*)(Ar + aRdOff + i * 512);                       \
        bf[i] = *(const bf16x8*)(Br + bRdOff + i * 512);                       \
    }                                                                          \
    if (PF) {                                                                  \
        GLOAD_LDS16(ap0 + kn, &As[((T) + 3) & 3][0] + aoff0);                  \
        GLOAD_LDS16(ap1 + kn, &As[((T) + 3) & 3][0] + aoff1);                  \
    }                                                                          \
    __builtin_amdgcn_s_barrier();                                              \
    asm volatile("s_waitcnt lgkmcnt(0)" ::: "memory");                         \
    __builtin_amdgcn_sched_barrier(0);                                         \
    __builtin_amdgcn_s_setprio(1);                                             \
    _Pragma("unroll")                                                          \
    for (int mi = 0; mi < 4; mi++)                                             \
        _Pragma("unroll")                                                      \
        for (int nj = 0; nj < 4; nj++)                                         \
            acc[mi][nj] = __builtin_amdgcn_mfma_f32_16x16x32_bf16(             \
                af[mi], bf[nj], acc[mi][nj], 0, 0, 0);                         \
    __builtin_amdgcn_s_setprio(0);                                             \
    __builtin_amdgcn_s_barrier();                                              \
    _Pragma("unroll")                                                          \
    for (int i = 4; i < 8; i++)                                                \
        af[i] = *(const bf16x8*)(Ar + aRdOff + i * 512);                       \
    if (PF) {                                                                  \
        GLOAD_LDS16(bp0 + kn, &Bs[((T) + 3) & 3][0] + aoff0);                  \
        GLOAD_LDS16(bp1 + kn, &Bs[((T) + 3) & 3][0] + aoff1);                  \
    }                                                                          \
    __builtin_amdgcn_s_barrier();                                              \
    asm volatile("s_waitcnt lgkmcnt(0)" ::: "memory");                         \
    __builtin_amdgcn_sched_barrier(0);                                         \
    __builtin_amdgcn_s_setprio(1);                                             \
    _Pragma("unroll")                                                          \
    for (int mi = 4; mi < 8; mi++)                                             \
        _Pragma("unroll")                                                      \
        for (int nj = 0; nj < 4; nj++)                                         \
            acc[mi][nj] = __builtin_amdgcn_mfma_f32_16x16x32_bf16(             \
                af[mi], bf[nj], acc[mi][nj], 0, 0, 0);                         \
    __builtin_amdgcn_s_setprio(0);                                             \
    if ((W) == 8)      asm volatile("s_waitcnt vmcnt(8)" ::: "memory");        \
    else if ((W) == 4) asm volatile("s_waitcnt vmcnt(4)" ::: "memory");        \
    else if ((W) == 0) asm volatile("s_waitcnt vmcnt(0)" ::: "memory");        \
    if ((W) >= 0) __builtin_amdgcn_s_barrier();                                \
}

template <int KD, bool GATHER, bool SILU>
__global__ __launch_bounds__(512, 1)
void k_moe_gemm(const unsigned short* __restrict__ Ab,
                const unsigned short* __restrict__ Bt,
                unsigned short* __restrict__ Cout,
                const int* __restrict__ tok,
                const int* __restrict__ cnt) {
    const int tid  = threadIdx.x;
    const int lane = tid & 63;
    const int wv   = tid >> 6;                        // 0..7

    // ---- in-kernel tile table (256-row granule) ----
    int c_l = (lane < NEXP) ? min(cnt[lane], CAP) : ((lane == NEXP) ? TT : 0);
    int nt_l = (c_l + 255) >> 8;
    int pre = nt_l;
#pragma unroll
    for (int d = 1; d < 64; d <<= 1) {
        int up = __shfl_up(pre, d);
        if (lane >= d) pre += up;
    }
    const int ntl = __shfl(pre, 63);          // total live tiles
    const int chunk = (ntl + 7) >> 3;         // tiles per XCD
    const int c_xcd = blockIdx.x;             // == XCD (round-robin)
    const int qy = blockIdx.y;
    if ((qy >> 2) >= chunk) return;
    const int j = c_xcd * chunk + (qy >> 2);  // tile index
    if (j >= ntl) return;
    const int nt = qy & 3;                    // n-tile within row
    const int start_l = pre - nt_l;           // exclusive prefix
    const bool mine = (j >= start_l) && (j < start_l + nt_l);
    const unsigned long long bl = __ballot(mine);
    const int e_lane = __ffsll((long long)bl) - 1;
    const int e  = e_lane;
    const int mt = j - __shfl(start_l, e_lane);
    const int cE = __shfl(c_l, e_lane);

    const int slotbase = (e < NEXP) ? e * CAP : SHARED_BASE;
    const int m0 = mt * 256;
    const int rowsv = min(256, cE - m0);

    const unsigned short* Bte = Bt + (size_t)e * (1024 * KD);

    __shared__ unsigned short As[4][256 * 32];        // 64 KB
    __shared__ unsigned short Bs[4][256 * 32];        // 64 KB

    // staging: each wave stages its 32 A-rows + 32 B-rows; swizzled k-seg
    const int rr  = lane >> 2;
    const int seg = (lane & 3) ^ ((lane >> 3) & 3);
    const int r0 = wv * 32 + rr;                      // 0..255
    const int r1 = r0 + 16;

    int ga0 = m0 + r0, ga1 = m0 + r1;
    int ra0, ra1;
    if (GATHER) {
        ra0 = (ga0 < cE) ? tok[slotbase + ga0] : 0;  // clamp: rows discarded
        ra1 = (ga1 < cE) ? tok[slotbase + ga1] : 0;
    } else {
        ra0 = slotbase + ga0;
        ra1 = slotbase + ga1;
    }
    const unsigned short* ap0 = Ab + (size_t)ra0 * KD + seg * 8;
    const unsigned short* ap1 = Ab + (size_t)ra1 * KD + seg * 8;

    int br0, br1;
    if (SILU) {
        // local B row r: group g=r>>6 (one wave's 64 rows = 32 gate + 32 up
        // for cols nt*128 + g*32 + 0..31)
        int in0 = r0 & 63, in1 = r1 & 63;
        int c0 = nt * 128 + (r0 >> 6) * 32 + (in0 & 31);
        int c1 = nt * 128 + (r1 >> 6) * 32 + (in1 & 31);
        br0 = (in0 < 32) ? c0 : 512 + c0;
        br1 = (in1 < 32) ? c1 : 512 + c1;
    } else {
        br0 = nt * 256 + r0;
        br1 = nt * 256 + r1;
    }
    const unsigned short* bp0 = Bte + (size_t)br0 * KD + seg * 8;
    const unsigned short* bp1 = Bte + (size_t)br1 * KD + seg * 8;

    const int aoff0 = (wv * 32) * 32, aoff1 = (wv * 32 + 16) * 32;

    f32x4 acc[8][4];
#pragma unroll
    for (int i = 0; i < 8; i++)
#pragma unroll
        for (int j2 = 0; j2 < 4; j2++) acc[i][j2] = (f32x4)(0.0f);

    const int mrow = lane & 15;
    const int quad = lane >> 4;
    const int wm = wv >> 2, wn = wv & 3;             // wave tile 128x64
    const int sw = (quad ^ ((mrow >> 1) & 3)) * 8;   // swizzled k-slot (elems)

    const int aRdOff = (wm * 128 + mrow) * 32 + sw;
    const int bRdOff = (wn * 64 + mrow) * 32 + sw;

    // prologue: stage chunks 0..2 into ring bufs 0..2 (12 loads/wave)
#pragma unroll
    for (int c = 0; c < 3; c++) {
        GLOAD_LDS16(ap0 + c * 32, &As[c][0] + aoff0);
        GLOAD_LDS16(ap1 + c * 32, &As[c][0] + aoff1);
        GLOAD_LDS16(bp0 + c * 32, &Bs[c][0] + aoff0);
        GLOAD_LDS16(bp1 + c * 32, &Bs[c][0] + aoff1);
    }
    asm volatile("s_waitcnt vmcnt(8)" ::: "memory");   // chunk 0 landed
    __builtin_amdgcn_s_barrier();

    const int NTCH = KD / 32;
    for (int t = 0; t < NTCH - 3; ++t) GEMM_ITER(t, true, 8);
    GEMM_ITER(NTCH - 3, false, 4);
    GEMM_ITER(NTCH - 2, false, 0);
    GEMM_ITER(NTCH - 1, false, -1);

    // C/D layout (verified m89/m91): col = lane&15, row = quad*4 + reg
    if (SILU) {
#pragma unroll
        for (int mi = 0; mi < 8; mi++)
#pragma unroll
            for (int nj = 0; nj < 2; nj++) {
                f32x4 g = acc[mi][nj];
                f32x4 u = acc[mi][nj + 2];
#pragma unroll
                for (int r = 0; r < 4; r++) {
                    int rloc = wm * 128 + mi * 16 + quad * 4 + r;
                    if (rloc < rowsv) {
                        float gv = g[r], uv = u[r];
                        float a = (gv / (1.f + __expf(-gv))) * uv;   // silu(g)*u
                        int c = nt * 128 + wn * 32 + nj * 16 + mrow;
                        Cout[(size_t)(slotbase + m0 + rloc) * ID + c] = f2bf(a);
                    }
                }
            }
    } else {
#pragma unroll
        for (int mi = 0; mi < 8; mi++)
#pragma unroll
            for (int nj = 0; nj < 4; nj++) {
                f32x4 v = acc[mi][nj];
#pragma unroll
                for (int r = 0; r < 4; r++) {
                    int rloc = wm * 128 + mi * 16 + quad * 4 + r;
                    if (rloc < rowsv) {
                        int c = nt * 256 + wn * 64 + nj * 16 + mrow;
                        Cout[(size_t)(slotbase + m0 + rloc) * HD + c] = f2bf(v[r]);
                    }
                }
            }
    }
}

// ---------------- combine: out[t] = shared + sum_k w_k * eout[slot_k] ------
__global__ __launch_bounds__(256)
void k_combine(const unsigned short* __restrict__ eout,
               const int* __restrict__ smap,
               const float* __restrict__ wgt,
               float* __restrict__ out) {
    const int t = blockIdx.x;
    const int h0 = threadIdx.x * 4;
    ushort4 q = *(const ushort4*)(eout + (size_t)(SHARED_BASE + t) * HD + h0);
    float a0 = bf2f(q.x), a1 = bf2f(q.y), a2 = bf2f(q.z), a3 = bf2f(q.w);
#pragma unroll
    for (int r = 0; r < TOPK; r++) {
        int slot = smap[t * TOPK + r];
        if (slot >= 0) {
            float w = wgt[slot];
            ushort4 e4 = *(const ushort4*)(eout + (size_t)slot * HD + h0);
            a0 += w * bf2f(e4.x); a1 += w * bf2f(e4.y);
            a2 += w * bf2f(e4.z); a3 += w * bf2f(e4.w);
        }
    }
    float4 o; o.x = a0; o.y = a1; o.z = a2; o.w = a3;
    *(float4*)(out + (size_t)t * HD + h0) = o;
}

// ---------------- launch ----------------
extern "C" void kernel_launch(void* const* d_in, const int* in_sizes, int n_in,
                              void* d_out, int out_size, void* d_ws, size_t ws_size,
                              hipStream_t stream) {
    const float* x   = (const float*)d_in[0];   // [T,H]
    const float* gw  = (const float*)d_in[1];   // [E,H]
    const float* wgu = (const float*)d_in[2];   // [E,H,2I]
    const float* wdn = (const float*)d_in[3];   // [E,I,H]
    const float* sgu = (const float*)d_in[4];   // [H,2I]
    const float* sdn = (const float*)d_in[5];   // [I,H]
    float* out = (float*)d_out;

    char* w = (char*)d_ws;
    size_t off = 0;
    int* cnt = (int*)(w + off);                       off += 256;
    unsigned short* xb     = (unsigned short*)(w + off); off += (size_t)TT * HD * 2;            // 8 MB
    unsigned short* wgup_t = (unsigned short*)(w + off); off += (size_t)33 * 1024 * 1024 * 2;   // 66 MB
    unsigned short* wdn_t  = (unsigned short*)(w + off); off += (size_t)33 * 1024 * 512 * 2;    // 33 MB
    unsigned short* act    = (unsigned short*)(w + off); off += (size_t)NSLOT * ID * 2;         // 36 MB
    unsigned short* eout   = (unsigned short*)(w + off); off += (size_t)NSLOT * HD * 2;         // 72 MB
    int*   tok    = (int*)(w + off);   off += (size_t)NSLOT * 4;
    float* wgt    = (float*)(w + off); off += (size_t)NSLOT * 4;
    int*   smap   = (int*)(w + off);   off += (size_t)TT * TOPK * 4;
    int*   choice = (int*)(w + off);   off += (size_t)TT * TOPK * 4;
    float* cw     = (float*)(w + off); off += (size_t)TT * TOPK * 4;

    // router partials (8 MB) alias eout: consumed by k_topk before GEMM2
    // produces eout — stream-ordered, no overlap.
    float* part = (float*)eout;

    // weights -> bf16, K-major ([N][K]); shared expert appended as slot 32
    k_transpose_bf16<<<dim3(16, 16, 33), 256, 0, stream>>>(wgu, sgu, wgup_t, 1024, 1024);
    k_transpose_bf16<<<dim3(16, 8, 33),  256, 0, stream>>>(wdn, sdn, wdn_t, 512, 1024);

    // router: split-K fp32 logits GEMM (+ fused x->bf16), top-4, slot scan
    k_logits<<<dim3(16, KSPLIT), 256, 0, stream>>>(x, gw, part, xb);
    k_topk<<<TT / 4, 256, 0, stream>>>(part, choice, cw, tok, wgt);
    k_assign<<<NEXP, 1024, 0, stream>>>(choice, cw, cnt, tok, wgt, smap);

    // GEMM1: gathered x @ gate_up^T, fused silu*mul -> act (NT=4: 128 cols/tile)
    k_moe_gemm<1024, true, true><<<dim3(8, GRIDY), 512, 0, stream>>>(xb, wgup_t, act, tok, cnt);
    // GEMM2: act @ down^T -> eout (NT=4: 256 cols/tile)
    k_moe_gemm<512, false, false><<<dim3(8, GRIDY), 512, 0, stream>>>(act, wdn_t, eout, tok, cnt);

    k_combine<<<TT, 256, 0, stream>>>(eout, smap, wgt, out);
}

// Round 7
// 441.249 us; speedup vs baseline: 1.0482x; 1.0482x over previous
//
#include <hip/hip_runtime.h>
#include <cstdint>
#include <cstddef>

// ---------------- problem constants ----------------
#define NEXP   32          // routed experts
#define TOPK   4
#define HD     1024        // hidden
#define ID     512         // intermediate
#define TT     4096        // tokens (B*S)
#define CAP    1024        // capacity per routed expert
#define SHARED_BASE (NEXP*CAP)        // 32768 : slot base of shared-expert rows
#define NSLOT  (NEXP*CAP + TT)        // 36864 total slot rows
#define MAXTILES 320       // grid-y: (qy>>3) up to 40 >= worst chunk 36

#define KSPLIT 16          // router split-K
#define KCH    64          // K per logits block
#define KSUB   32          // LDS sub-chunk

typedef __attribute__((ext_vector_type(4))) float f32x4;
typedef __bf16 bf16x8 __attribute__((ext_vector_type(8)));

__device__ __forceinline__ unsigned short f2bf(float f) {
    union { float f; unsigned int u; } v; v.f = f;
    unsigned int u = v.u;
    u = (u + 0x7FFFu + ((u >> 16) & 1u)) >> 16;   // RNE
    return (unsigned short)u;
}
__device__ __forceinline__ float bf2f(unsigned short s) {
    union { unsigned int u; float f; } v; v.u = ((unsigned int)s) << 16;
    return v.f;
}

#define GLOAD_LDS16(g, l)                                                     \
    __builtin_amdgcn_global_load_lds(                                         \
        (__attribute__((address_space(1))) void*)(g),                         \
        (__attribute__((address_space(3))) void*)(l), 16, 0, 0)

// ---------------- fp32 [K][N] -> bf16 [N][K] transpose ---------------------
// z < NEXP: expert z of src; z == NEXP: shared-expert srcS (appended slot).
__global__ void k_transpose_bf16(const float* __restrict__ src,
                                 const float* __restrict__ srcS,
                                 unsigned short* __restrict__ dst,
                                 int K, int N) {
    __shared__ float ld[64][65];      // +1 pad: conflict-free transpose
    const size_t esz = (size_t)K * N;
    const int z = blockIdx.z;
    const float* s = (z < NEXP) ? src + (size_t)z * esz : srcS;
    dst += (size_t)z * esz;
    const int n0 = blockIdx.x * 64, k0 = blockIdx.y * 64;
    const int tid = threadIdx.x;
    const int c4 = (tid & 15) * 4;
    const int rbase = tid >> 4;        // 0..15
#pragma unroll
    for (int p = 0; p < 4; p++) {
        int row = rbase + p * 16;
        float4 v = *(const float4*)(s + (size_t)(k0 + row) * N + n0 + c4);
        ld[row][c4 + 0] = v.x; ld[row][c4 + 1] = v.y;
        ld[row][c4 + 2] = v.z; ld[row][c4 + 3] = v.w;
    }
    __syncthreads();
    const int n  = tid >> 2;           // 0..63
    const int ks = (tid & 3) * 16;     // k segment
    unsigned short tmp[16];
#pragma unroll
    for (int i = 0; i < 16; i++) tmp[i] = f2bf(ld[ks + i][n]);
    uint4 a, b;
    a.x = tmp[0] | (tmp[1] << 16);  a.y = tmp[2] | (tmp[3] << 16);
    a.z = tmp[4] | (tmp[5] << 16);  a.w = tmp[6] | (tmp[7] << 16);
    b.x = tmp[8] | (tmp[9] << 16);  b.y = tmp[10] | (tmp[11] << 16);
    b.z = tmp[12] | (tmp[13] << 16); b.w = tmp[14] | (tmp[15] << 16);
    unsigned short* op = dst + (size_t)(n0 + n) * K + k0 + ks;
    *(uint4*)op = a;
    *(uint4*)(op + 8) = b;
}

// ---------------- router part 1: fp32 logits + fused x->bf16 convert ------
__global__ __launch_bounds__(256)
void k_logits(const float* __restrict__ x, const float* __restrict__ gw,
              float* __restrict__ part, unsigned short* __restrict__ xb) {
    __shared__ float xsT[KSUB][260];
    __shared__ float gsT[KSUB][36];
    const int tid = threadIdx.x;
    const int lane = tid & 63, wv = tid >> 6;
    const int tg = lane >> 2, eg = lane & 3;
    const int t0 = blockIdx.x * 256;
    const int kbase = blockIdx.y * KCH;
    const int tbase = wv * 64 + tg * 4;
    const int ebase = eg * 8;

    float acc[4][8];
#pragma unroll
    for (int j = 0; j < 4; j++)
#pragma unroll
        for (int i = 0; i < 8; i++) acc[j][i] = 0.f;

    for (int ks = 0; ks < KCH; ks += KSUB) {
        const int k0 = kbase + ks;
        if (ks > 0) __syncthreads();
#pragma unroll
        for (int p = 0; p < 8; p++) {
            int vid = p * 256 + tid;
            int t = vid >> 3, kq = (vid & 7) * 4;
            float4 v = *(const float4*)(x + (size_t)(t0 + t) * HD + k0 + kq);
            xsT[kq + 0][t] = v.x; xsT[kq + 1][t] = v.y;
            xsT[kq + 2][t] = v.z; xsT[kq + 3][t] = v.w;
            ushort4 o;
            o.x = f2bf(v.x); o.y = f2bf(v.y); o.z = f2bf(v.z); o.w = f2bf(v.w);
            *(ushort4*)(xb + (size_t)(t0 + t) * HD + k0 + kq) = o;
        }
#pragma unroll
        for (int p = 0; p < 4; p++) {
            int vid = p * 256 + tid;
            int e = vid >> 5, k = vid & 31;
            gsT[k][e] = gw[(size_t)e * HD + k0 + k];
        }
        __syncthreads();
#pragma unroll 4
        for (int k = 0; k < KSUB; k++) {
            float4 xv = *(const float4*)&xsT[k][tbase];
            float4 g0 = *(const float4*)&gsT[k][ebase];
            float4 g1 = *(const float4*)&gsT[k][ebase + 4];
            float xa[4] = {xv.x, xv.y, xv.z, xv.w};
#pragma unroll
            for (int j = 0; j < 4; j++) {
                acc[j][0] += xa[j] * g0.x; acc[j][1] += xa[j] * g0.y;
                acc[j][2] += xa[j] * g0.z; acc[j][3] += xa[j] * g0.w;
                acc[j][4] += xa[j] * g1.x; acc[j][5] += xa[j] * g1.y;
                acc[j][6] += xa[j] * g1.z; acc[j][7] += xa[j] * g1.w;
            }
        }
    }
    const size_t base = ((size_t)blockIdx.y * TT + (t0 + tbase)) * 32 + ebase;
#pragma unroll
    for (int j = 0; j < 4; j++) {
        float4 w0, w1;
        w0.x = acc[j][0]; w0.y = acc[j][1]; w0.z = acc[j][2]; w0.w = acc[j][3];
        w1.x = acc[j][4]; w1.y = acc[j][5]; w1.z = acc[j][6]; w1.w = acc[j][7];
        *(float4*)(part + base + (size_t)j * 32) = w0;
        *(float4*)(part + base + (size_t)j * 32 + 4) = w1;
    }
}

// ---------------- router part 2: reduce partials, top-4 (NO atomics) ------
__global__ __launch_bounds__(256)
void k_topk(const float* __restrict__ part,
            int* __restrict__ choice, float* __restrict__ cw,
            int* __restrict__ tok, float* __restrict__ wgt) {
    const int lane = threadIdx.x & 63, wv = threadIdx.x >> 6;
    const int t = blockIdx.x * 4 + wv;
    const int e = lane & 31;
    const int sbase = (lane >> 5) * 8;
    float v = 0.f;
#pragma unroll
    for (int s = 0; s < 8; s++)
        v += part[((size_t)(sbase + s) * TT + t) * 32 + e];
    v += __shfl_xor(v, 32);
    float sc = (lane < 32) ? v : -INFINITY;

    float lv[TOPK]; int le[TOPK];
#pragma unroll
    for (int r = 0; r < TOPK; r++) {
        float m = sc;
#pragma unroll
        for (int d = 1; d < 64; d <<= 1) m = fmaxf(m, __shfl_xor(m, d));
        unsigned long long ball = __ballot(sc == m);
        int widx = __ffsll(ball) - 1;       // lowest lane on tie = jax top_k
        lv[r] = m; le[r] = widx;
        if (lane == widx) sc = -INFINITY;
    }
    if (lane == 0) {
        float wv4[TOPK], wsum = 0.f;
#pragma unroll
        for (int r = 0; r < TOPK; r++) { wv4[r] = __expf(lv[r] - lv[0]); wsum += wv4[r]; }
#pragma unroll
        for (int r = 0; r < TOPK; r++) {
            choice[t * TOPK + r] = le[r];
            cw[t * TOPK + r] = wv4[r] / wsum;
        }
        tok[SHARED_BASE + t] = t;            // shared-expert identity slot
        wgt[SHARED_BASE + t] = 1.0f;
    }
}

// ---------------- slot assignment: deterministic ballot-scan, 1 blk/expert -
__global__ __launch_bounds__(1024)
void k_assign(const int* __restrict__ choice, const float* __restrict__ cw,
              int* __restrict__ cnt, int* __restrict__ tok,
              float* __restrict__ wgt, int* __restrict__ smap) {
    const int e = blockIdx.x;
    const int tid = threadIdx.x, lane = tid & 63, wv = tid >> 6;
    __shared__ int wtot[16];
    int running = 0;
    for (int it = 0; it < (TT * TOPK) / 1024; it++) {
        const int i = it * 1024 + tid;
        const bool match = (choice[i] == e);
        unsigned long long ball = __ballot(match);
        int wt = __popcll(ball);
        int wpre = __popcll(ball & ((1ull << lane) - 1ull));
        if (lane == 0) wtot[wv] = wt;
        __syncthreads();
        int woff = 0, tot = 0;
#pragma unroll
        for (int w = 0; w < 16; w++) { int c = wtot[w]; tot += c; if (w < wv) woff += c; }
        int pos = running + woff + wpre;
        running += tot;
        __syncthreads();
        if (match) {
            if (pos < CAP) {
                int slot = e * CAP + pos;
                tok[slot] = i >> 2;          // token id
                wgt[slot] = cw[i];
                smap[i] = slot;
            } else {
                smap[i] = -1;                // overflow dropped (P ~ 0)
            }
        }
    }
    if (tid == 0) cnt[e] = min(running, CAP);
}

// ---------------- grouped GEMM: 128x128 tile, BK=64, 2-stage --------------
// Why 128x128: per-wave acc must stay at 64 f32 regs -> total ~140/wave ->
// 2 waves/SIMD -> 2 blocks/CU co-resident (256x256 needs 128 acc regs ->
// 1 block/CU lockstep, measured 102us in R4/R6). Why BK=64: halves the
// {vmcnt-drain + s_barrier} frequency vs BK=32 (one sync per 128 MFMA);
// LDS 2x(16+16KB)=64KB costs nothing since occupancy is register-bound.
// Loop: wait vmcnt(0) (loads had a full 64-K iteration to land -> near-free)
// -> barrier -> prefetch k+64 into buf p^1 (read last iter; all its reads
// were consumed before any wave reached this barrier) -> 2x{8 ds_read_b128
// + 16 MFMA}.
// LDS swizzle (64-elem rows, 8x16B segs): slot s of row r holds k-seg
// s^(r&7); read slot = (kk*4+quad)^(mrow&7) -> <=2-way aliasing per
// 16-lane phase (free, m136). Source-address pre-swizzle keeps the
// global_load_lds dest linear (m173 pattern).
// In-kernel tile table (33-lane prefix scan over cnt) + XCD chunking (T1).
template <int KD, bool GATHER, bool SILU>
__global__ __launch_bounds__(256)
void k_moe_gemm(const unsigned short* __restrict__ Ab,
                const unsigned short* __restrict__ Bt,
                unsigned short* __restrict__ Cout,
                const int* __restrict__ tok,
                const int* __restrict__ cnt) {
    const int tid  = threadIdx.x;
    const int lane = tid & 63;
    const int wv   = tid >> 6;

    // ---- in-kernel tile table ----
    int c_l = (lane < NEXP) ? min(cnt[lane], CAP) : ((lane == NEXP) ? TT : 0);
    int nt_l = (c_l + 127) >> 7;              // 128-row m-tiles of expert 'lane'
    int pre = nt_l;
#pragma unroll
    for (int d = 1; d < 64; d <<= 1) {
        int up = __shfl_up(pre, d);
        if (lane >= d) pre += up;
    }
    const int ntl = __shfl(pre, 63);          // total live tiles
    const int chunk = (ntl + 7) >> 3;         // tiles per XCD
    const int c_xcd = blockIdx.x;             // == XCD (round-robin)
    const int qy = blockIdx.y;
    if ((qy >> 3) >= chunk) return;
    const int j = c_xcd * chunk + (qy >> 3);  // tile index
    if (j >= ntl) return;
    const int nt = qy & 7;                    // n-tile within row
    const int start_l = pre - nt_l;           // exclusive prefix
    const bool mine = (j >= start_l) && (j < start_l + nt_l);
    const unsigned long long bl = __ballot(mine);
    const int e_lane = __ffsll((long long)bl) - 1;
    const int e  = e_lane;
    const int mt = j - __shfl(start_l, e_lane);
    const int cE = __shfl(c_l, e_lane);

    const int slotbase = (e < NEXP) ? e * CAP : SHARED_BASE;
    const int m0 = mt * 128;
    const int rowsv = min(128, cE - m0);

    const unsigned short* Bte = Bt + (size_t)e * (1024 * KD);

    __shared__ unsigned short As[2][128 * 64];   // 16 KB each
    __shared__ unsigned short Bs[2][128 * 64];

    // staging: wave stages its 32 A-rows + 32 B-rows in 4 loads each
    // (8 rows per load, 64-K per row). Lane: row sub = lane>>3, seg = lane&7;
    // swizzled source k-seg = (lane&7) ^ (lane>>3) (row&7 == lane>>3).
    const int rr8  = lane >> 3;                  // 0..7
    const int seg8 = (lane & 7) ^ rr8;           // 16B k-seg to fetch

    const unsigned short* ap[4];
    const unsigned short* bp[4];
#pragma unroll
    for (int pp = 0; pp < 4; pp++) {
        int r = wv * 32 + pp * 8 + rr8;          // local row 0..127
        int ga = m0 + r;
        int ra;
        if (GATHER) {
            ra = (ga < cE) ? tok[slotbase + ga] : 0;   // clamp: rows discarded
        } else {
            ra = slotbase + ga;
        }
        ap[pp] = Ab + (size_t)ra * KD + seg8 * 8;
        int br;
        if (SILU) {
            // local B row r: 0..31 of each 64-half -> gate col, 32..63 -> up
            int in = r & 63;
            int c = nt * 64 + (r >> 6) * 32 + (in & 31);
            br = (in < 32) ? c : 512 + c;
        } else {
            br = nt * 128 + r;
        }
        bp[pp] = Bte + (size_t)br * KD + seg8 * 8;
    }

#define STAGE(P, K0)                                                          \
    {                                                                         \
        _Pragma("unroll")                                                     \
        for (int pp = 0; pp < 4; pp++) {                                      \
            GLOAD_LDS16(ap[pp] + (K0), &As[P][0] + (wv * 32 + pp * 8) * 64);  \
            GLOAD_LDS16(bp[pp] + (K0), &Bs[P][0] + (wv * 32 + pp * 8) * 64);  \
        }                                                                     \
    }

    f32x4 acc[4][4];
#pragma unroll
    for (int i = 0; i < 4; i++)
#pragma unroll
        for (int j2 = 0; j2 < 4; j2++) acc[i][j2] = (f32x4)(0.0f);

    const int mrow = lane & 15;
    const int quad = lane >> 4;
    const int wm = wv >> 1, wn = wv & 1;
    const int sw0 = ((quad ^ (mrow & 7)) * 8);   // swizzled k-slot, kk=0 (elems)

    const int aRdBase = (wm * 64 + mrow) * 64;
    const int bRdBase = (wn * 64 + mrow) * 64;

    // prologue: stage chunk 0 into buffer 0
    STAGE(0, 0);

    int p = 0;
    for (int k0 = 0; k0 < KD; k0 += 64) {
        asm volatile("s_waitcnt vmcnt(0) lgkmcnt(0)" ::: "memory");
        __builtin_amdgcn_s_barrier();
        asm volatile("" ::: "memory");       // keep prefetch/reads below barrier

        if (k0 + 64 < KD) {
            if (p == 0) STAGE(1, k0 + 64) else STAGE(0, k0 + 64);
        }

#pragma unroll
        for (int kk = 0; kk < 2; kk++) {
            const int swk = sw0 ^ (kk << 5);     // kk flips slot bit2 (+32 elems)
            bf16x8 af[4], bf[4];
#pragma unroll
            for (int i = 0; i < 4; i++) {
                af[i] = *(const bf16x8*)(&As[p][0] + aRdBase + i * 16 * 64 + swk);
                bf[i] = *(const bf16x8*)(&Bs[p][0] + bRdBase + i * 16 * 64 + swk);
            }
#pragma unroll
            for (int mi = 0; mi < 4; mi++)
#pragma unroll
                for (int nj = 0; nj < 4; nj++)
                    acc[mi][nj] = __builtin_amdgcn_mfma_f32_16x16x32_bf16(
                        af[mi], bf[nj], acc[mi][nj], 0, 0, 0);
        }
        p ^= 1;
        // overwrite of the buffer just read happens only after the NEXT
        // barrier; every wave consumed (completed) its reads before that.
    }

    // C/D layout (verified m89/m91): col = lane&15, row = quad*4 + reg
    if (SILU) {
#pragma unroll
        for (int mi = 0; mi < 4; mi++)
#pragma unroll
            for (int nj = 0; nj < 2; nj++) {
                f32x4 g = acc[mi][nj];
                f32x4 u = acc[mi][nj + 2];
#pragma unroll
                for (int r = 0; r < 4; r++) {
                    int rloc = wm * 64 + mi * 16 + quad * 4 + r;
                    if (rloc < rowsv) {
                        float gv = g[r], uv = u[r];
                        float a = (gv / (1.f + __expf(-gv))) * uv;   // silu(g)*u
                        int c = nt * 64 + wn * 32 + nj * 16 + mrow;
                        Cout[(size_t)(slotbase + m0 + rloc) * ID + c] = f2bf(a);
                    }
                }
            }
    } else {
#pragma unroll
        for (int mi = 0; mi < 4; mi++)
#pragma unroll
            for (int nj = 0; nj < 4; nj++) {
                f32x4 v = acc[mi][nj];
#pragma unroll
                for (int r = 0; r < 4; r++) {
                    int rloc = wm * 64 + mi * 16 + quad * 4 + r;
                    if (rloc < rowsv) {
                        int c = nt * 128 + wn * 64 + nj * 16 + mrow;
                        Cout[(size_t)(slotbase + m0 + rloc) * HD + c] = f2bf(v[r]);
                    }
                }
            }
    }
#undef STAGE
}

// ---------------- combine: out[t] = shared + sum_k w_k * eout[slot_k] ------
__global__ __launch_bounds__(256)
void k_combine(const unsigned short* __restrict__ eout,
               const int* __restrict__ smap,
               const float* __restrict__ wgt,
               float* __restrict__ out) {
    const int t = blockIdx.x;
    const int h0 = threadIdx.x * 4;
    ushort4 q = *(const ushort4*)(eout + (size_t)(SHARED_BASE + t) * HD + h0);
    float a0 = bf2f(q.x), a1 = bf2f(q.y), a2 = bf2f(q.z), a3 = bf2f(q.w);
#pragma unroll
    for (int r = 0; r < TOPK; r++) {
        int slot = smap[t * TOPK + r];
        if (slot >= 0) {
            float w = wgt[slot];
            ushort4 e4 = *(const ushort4*)(eout + (size_t)slot * HD + h0);
            a0 += w * bf2f(e4.x); a1 += w * bf2f(e4.y);
            a2 += w * bf2f(e4.z); a3 += w * bf2f(e4.w);
        }
    }
    float4 o; o.x = a0; o.y = a1; o.z = a2; o.w = a3;
    *(float4*)(out + (size_t)t * HD + h0) = o;
}

// ---------------- launch ----------------
extern "C" void kernel_launch(void* const* d_in, const int* in_sizes, int n_in,
                              void* d_out, int out_size, void* d_ws, size_t ws_size,
                              hipStream_t stream) {
    const float* x   = (const float*)d_in[0];   // [T,H]
    const float* gw  = (const float*)d_in[1];   // [E,H]
    const float* wgu = (const float*)d_in[2];   // [E,H,2I]
    const float* wdn = (const float*)d_in[3];   // [E,I,H]
    const float* sgu = (const float*)d_in[4];   // [H,2I]
    const float* sdn = (const float*)d_in[5];   // [I,H]
    float* out = (float*)d_out;

    char* w = (char*)d_ws;
    size_t off = 0;
    int* cnt = (int*)(w + off);                       off += 256;
    unsigned short* xb     = (unsigned short*)(w + off); off += (size_t)TT * HD * 2;            // 8 MB
    unsigned short* wgup_t = (unsigned short*)(w + off); off += (size_t)33 * 1024 * 1024 * 2;   // 66 MB
    unsigned short* wdn_t  = (unsigned short*)(w + off); off += (size_t)33 * 1024 * 512 * 2;    // 33 MB
    unsigned short* act    = (unsigned short*)(w + off); off += (size_t)NSLOT * ID * 2;         // 36 MB
    unsigned short* eout   = (unsigned short*)(w + off); off += (size_t)NSLOT * HD * 2;         // 72 MB
    int*   tok    = (int*)(w + off);   off += (size_t)NSLOT * 4;
    float* wgt    = (float*)(w + off); off += (size_t)NSLOT * 4;
    int*   smap   = (int*)(w + off);   off += (size_t)TT * TOPK * 4;
    int*   choice = (int*)(w + off);   off += (size_t)TT * TOPK * 4;
    float* cw     = (float*)(w + off); off += (size_t)TT * TOPK * 4;

    // router partials (8 MB) alias eout: consumed by k_topk before GEMM2
    // produces eout — stream-ordered, no overlap.
    float* part = (float*)eout;

    // weights -> bf16, K-major ([N][K]); shared expert appended as slot 32
    k_transpose_bf16<<<dim3(16, 16, 33), 256, 0, stream>>>(wgu, sgu, wgup_t, 1024, 1024);
    k_transpose_bf16<<<dim3(16, 8, 33),  256, 0, stream>>>(wdn, sdn, wdn_t, 512, 1024);

    // router: split-K fp32 logits GEMM (+ fused x->bf16), top-4, slot scan
    k_logits<<<dim3(16, KSPLIT), 256, 0, stream>>>(x, gw, part, xb);
    k_topk<<<TT / 4, 256, 0, stream>>>(part, choice, cw, tok, wgt);
    k_assign<<<NEXP, 1024, 0, stream>>>(choice, cw, cnt, tok, wgt, smap);

    // GEMM1: gathered x @ gate_up^T, fused silu*mul -> act
    k_moe_gemm<1024, true, true><<<dim3(8, MAXTILES), 256, 0, stream>>>(xb, wgup_t, act, tok, cnt);
    // GEMM2: act @ down^T -> eout
    k_moe_gemm<512, false, false><<<dim3(8, MAXTILES), 256, 0, stream>>>(act, wdn_t, eout, tok, cnt);

    k_combine<<<TT, 256, 0, stream>>>(eout, smap, wgt, out);
}

// Round 8
// 425.091 us; speedup vs baseline: 1.0881x; 1.0380x over previous
//
#include <hip/hip_runtime.h>
#include <cstdint>
#include <cstddef>

// ---------------- problem constants ----------------
#define NEXP   32          // routed experts
#define TOPK   4
#define HD     1024        // hidden
#define ID     512         // intermediate
#define TT     4096        // tokens (B*S)
#define CAP    1024        // capacity per routed expert
#define SHARED_BASE (NEXP*CAP)        // 32768 : slot base of shared-expert rows
#define NSLOT  (NEXP*CAP + TT)        // 36864 total slot rows
#define MAXTILES 320       // grid-y: (qy>>3) up to 40 >= worst chunk 36

#define KSPLIT 16          // router split-K
#define KCH    64          // K per logits block
#define KSUB   32          // LDS sub-chunk

typedef __attribute__((ext_vector_type(4))) float f32x4;
typedef __bf16 bf16x8 __attribute__((ext_vector_type(8)));

__device__ __forceinline__ unsigned short f2bf(float f) {
    union { float f; unsigned int u; } v; v.f = f;
    unsigned int u = v.u;
    u = (u + 0x7FFFu + ((u >> 16) & 1u)) >> 16;   // RNE
    return (unsigned short)u;
}
__device__ __forceinline__ float bf2f(unsigned short s) {
    union { unsigned int u; float f; } v; v.u = ((unsigned int)s) << 16;
    return v.f;
}

#define GLOAD_LDS16(g, l)                                                     \
    __builtin_amdgcn_global_load_lds(                                         \
        (__attribute__((address_space(1))) void*)(g),                         \
        (__attribute__((address_space(3))) void*)(l), 16, 0, 0)

// ---------------- fp32 [K][N] -> bf16 [N][K] transpose ---------------------
// z < NEXP: expert z of src; z == NEXP: shared-expert srcS (appended slot).
__global__ void k_transpose_bf16(const float* __restrict__ src,
                                 const float* __restrict__ srcS,
                                 unsigned short* __restrict__ dst,
                                 int K, int N) {
    __shared__ float ld[64][65];      // +1 pad: conflict-free transpose
    const size_t esz = (size_t)K * N;
    const int z = blockIdx.z;
    const float* s = (z < NEXP) ? src + (size_t)z * esz : srcS;
    dst += (size_t)z * esz;
    const int n0 = blockIdx.x * 64, k0 = blockIdx.y * 64;
    const int tid = threadIdx.x;
    const int c4 = (tid & 15) * 4;
    const int rbase = tid >> 4;        // 0..15
#pragma unroll
    for (int p = 0; p < 4; p++) {
        int row = rbase + p * 16;
        float4 v = *(const float4*)(s + (size_t)(k0 + row) * N + n0 + c4);
        ld[row][c4 + 0] = v.x; ld[row][c4 + 1] = v.y;
        ld[row][c4 + 2] = v.z; ld[row][c4 + 3] = v.w;
    }
    __syncthreads();
    const int n  = tid >> 2;           // 0..63
    const int ks = (tid & 3) * 16;     // k segment
    unsigned short tmp[16];
#pragma unroll
    for (int i = 0; i < 16; i++) tmp[i] = f2bf(ld[ks + i][n]);
    uint4 a, b;
    a.x = tmp[0] | (tmp[1] << 16);  a.y = tmp[2] | (tmp[3] << 16);
    a.z = tmp[4] | (tmp[5] << 16);  a.w = tmp[6] | (tmp[7] << 16);
    b.x = tmp[8] | (tmp[9] << 16);  b.y = tmp[10] | (tmp[11] << 16);
    b.z = tmp[12] | (tmp[13] << 16); b.w = tmp[14] | (tmp[15] << 16);
    unsigned short* op = dst + (size_t)(n0 + n) * K + k0 + ks;
    *(uint4*)op = a;
    *(uint4*)(op + 8) = b;
}

// ---------------- router part 1: fp32 logits + fused x->bf16 convert ------
__global__ __launch_bounds__(256)
void k_logits(const float* __restrict__ x, const float* __restrict__ gw,
              float* __restrict__ part, unsigned short* __restrict__ xb) {
    __shared__ float xsT[KSUB][260];
    __shared__ float gsT[KSUB][36];
    const int tid = threadIdx.x;
    const int lane = tid & 63, wv = tid >> 6;
    const int tg = lane >> 2, eg = lane & 3;
    const int t0 = blockIdx.x * 256;
    const int kbase = blockIdx.y * KCH;
    const int tbase = wv * 64 + tg * 4;
    const int ebase = eg * 8;

    float acc[4][8];
#pragma unroll
    for (int j = 0; j < 4; j++)
#pragma unroll
        for (int i = 0; i < 8; i++) acc[j][i] = 0.f;

    for (int ks = 0; ks < KCH; ks += KSUB) {
        const int k0 = kbase + ks;
        if (ks > 0) __syncthreads();
#pragma unroll
        for (int p = 0; p < 8; p++) {
            int vid = p * 256 + tid;
            int t = vid >> 3, kq = (vid & 7) * 4;
            float4 v = *(const float4*)(x + (size_t)(t0 + t) * HD + k0 + kq);
            xsT[kq + 0][t] = v.x; xsT[kq + 1][t] = v.y;
            xsT[kq + 2][t] = v.z; xsT[kq + 3][t] = v.w;
            ushort4 o;
            o.x = f2bf(v.x); o.y = f2bf(v.y); o.z = f2bf(v.z); o.w = f2bf(v.w);
            *(ushort4*)(xb + (size_t)(t0 + t) * HD + k0 + kq) = o;
        }
#pragma unroll
        for (int p = 0; p < 4; p++) {
            int vid = p * 256 + tid;
            int e = vid >> 5, k = vid & 31;
            gsT[k][e] = gw[(size_t)e * HD + k0 + k];
        }
        __syncthreads();
#pragma unroll 4
        for (int k = 0; k < KSUB; k++) {
            float4 xv = *(const float4*)&xsT[k][tbase];
            float4 g0 = *(const float4*)&gsT[k][ebase];
            float4 g1 = *(const float4*)&gsT[k][ebase + 4];
            float xa[4] = {xv.x, xv.y, xv.z, xv.w};
#pragma unroll
            for (int j = 0; j < 4; j++) {
                acc[j][0] += xa[j] * g0.x; acc[j][1] += xa[j] * g0.y;
                acc[j][2] += xa[j] * g0.z; acc[j][3] += xa[j] * g0.w;
                acc[j][4] += xa[j] * g1.x; acc[j][5] += xa[j] * g1.y;
                acc[j][6] += xa[j] * g1.z; acc[j][7] += xa[j] * g1.w;
            }
        }
    }
    const size_t base = ((size_t)blockIdx.y * TT + (t0 + tbase)) * 32 + ebase;
#pragma unroll
    for (int j = 0; j < 4; j++) {
        float4 w0, w1;
        w0.x = acc[j][0]; w0.y = acc[j][1]; w0.z = acc[j][2]; w0.w = acc[j][3];
        w1.x = acc[j][4]; w1.y = acc[j][5]; w1.z = acc[j][6]; w1.w = acc[j][7];
        *(float4*)(part + base + (size_t)j * 32) = w0;
        *(float4*)(part + base + (size_t)j * 32 + 4) = w1;
    }
}

// ---------------- router part 2: reduce partials, top-4 (NO atomics) ------
__global__ __launch_bounds__(256)
void k_topk(const float* __restrict__ part,
            int* __restrict__ choice, float* __restrict__ cw,
            int* __restrict__ tok, float* __restrict__ wgt) {
    const int lane = threadIdx.x & 63, wv = threadIdx.x >> 6;
    const int t = blockIdx.x * 4 + wv;
    const int e = lane & 31;
    const int sbase = (lane >> 5) * 8;
    float v = 0.f;
#pragma unroll
    for (int s = 0; s < 8; s++)
        v += part[((size_t)(sbase + s) * TT + t) * 32 + e];
    v += __shfl_xor(v, 32);
    float sc = (lane < 32) ? v : -INFINITY;

    float lv[TOPK]; int le[TOPK];
#pragma unroll
    for (int r = 0; r < TOPK; r++) {
        float m = sc;
#pragma unroll
        for (int d = 1; d < 64; d <<= 1) m = fmaxf(m, __shfl_xor(m, d));
        unsigned long long ball = __ballot(sc == m);
        int widx = __ffsll(ball) - 1;       // lowest lane on tie = jax top_k
        lv[r] = m; le[r] = widx;
        if (lane == widx) sc = -INFINITY;
    }
    if (lane == 0) {
        float wv4[TOPK], wsum = 0.f;
#pragma unroll
        for (int r = 0; r < TOPK; r++) { wv4[r] = __expf(lv[r] - lv[0]); wsum += wv4[r]; }
#pragma unroll
        for (int r = 0; r < TOPK; r++) {
            choice[t * TOPK + r] = le[r];
            cw[t * TOPK + r] = wv4[r] / wsum;
        }
        tok[SHARED_BASE + t] = t;            // shared-expert identity slot
        wgt[SHARED_BASE + t] = 1.0f;
    }
}

// ---------------- slot assignment: token-granular ballot-scan -------------
// One thread owns one TOKEN (int4 of its 4 choices) -> 4 iterations instead
// of 16, 8 barriers instead of 32. Order: threads ascend by token, slots
// ascend within thread == global i = t*4+r order == ref's stable sort.
__global__ __launch_bounds__(1024)
void k_assign(const int* __restrict__ choice, const float* __restrict__ cw,
              int* __restrict__ cnt, int* __restrict__ tok,
              float* __restrict__ wgt, int* __restrict__ smap) {
    const int e = blockIdx.x;
    const int tid = threadIdx.x, lane = tid & 63, wv = tid >> 6;
    __shared__ int wtot[16];
    int running = 0;
    for (int it = 0; it < TT / 1024; it++) {       // 4 iterations
        const int t = it * 1024 + tid;             // token id
        const int4   c4 = *(const int4*)(choice + t * 4);
        const float4 w4 = *(const float4*)(cw + t * 4);
        unsigned m = (unsigned)(c4.x == e) | ((unsigned)(c4.y == e) << 1)
                   | ((unsigned)(c4.z == e) << 2) | ((unsigned)(c4.w == e) << 3);
        int mc = __popc(m);                        // 0..4 (almost always 0/1)
        int pre = mc;                              // inclusive wave scan
#pragma unroll
        for (int d = 1; d < 64; d <<= 1) {
            int up = __shfl_up(pre, d);
            if (lane >= d) pre += up;
        }
        if (lane == 63) wtot[wv] = pre;            // wave total
        const int wpre = pre - mc;                 // exclusive within wave
        __syncthreads();
        int woff = 0, tot = 0;
#pragma unroll
        for (int w = 0; w < 16; w++) { int c = wtot[w]; tot += c; if (w < wv) woff += c; }
        int base = running + woff + wpre;
        running += tot;
        __syncthreads();
        if (m) {
            const float wa[4] = {w4.x, w4.y, w4.z, w4.w};
            int k = 0;
#pragma unroll
            for (int r = 0; r < 4; r++) {
                if (m & (1u << r)) {
                    int pos = base + k;
                    int i = t * 4 + r;
                    if (pos < CAP) {
                        int slot = e * CAP + pos;
                        tok[slot] = t;
                        wgt[slot] = wa[r];
                        smap[i] = slot;
                    } else {
                        smap[i] = -1;              // overflow dropped (P ~ 0)
                    }
                    k++;
                }
            }
        }
    }
    if (tid == 0) cnt[e] = min(running, CAP);
}

// ---------------- grouped GEMM: 128x128 tile, BK=32 ----------------------
// 3-stage LDS pipeline, 2 K-iters of prefetch lead (T3/T4):
//   per iter: s_waitcnt vmcnt(4) (only oldest stage drained) -> raw
//   s_barrier -> issue prefetch for k+2 into buf[(it+2)%3] -> ds_read + MFMA.
// 48KB LDS + ~140 regs/wave -> 3 blocks/CU co-resident (the occupancy that
// R6/R7 experiments proved dominant: 256x256 (1 blk/CU) = 102us, BK=64
// (2 blk/CU) = 83us, this = 78.6us).
// In-kernel tile table (33-lane prefix scan over cnt); XCD map (T1):
// grid (8, MAXTILES), linear id = bx + 8*by -> XCD == bx; XCD c owns a
// contiguous chunk of live tiles, 8 nt-blocks of one tile adjacent.
// LDS k-seg XOR swizzle (slot s of row r holds seg s^((r>>1)&3)): 0 conflicts.
template <int KD, bool GATHER, bool SILU>
__global__ __launch_bounds__(256)
void k_moe_gemm(const unsigned short* __restrict__ Ab,
                const unsigned short* __restrict__ Bt,
                unsigned short* __restrict__ Cout,
                const int* __restrict__ tok,
                const int* __restrict__ cnt) {
    const int tid  = threadIdx.x;
    const int lane = tid & 63;
    const int wv   = tid >> 6;

    // ---- in-kernel tile table ----
    int c_l = (lane < NEXP) ? min(cnt[lane], CAP) : ((lane == NEXP) ? TT : 0);
    int nt_l = (c_l + 127) >> 7;              // 128-row m-tiles of expert 'lane'
    int pre = nt_l;
#pragma unroll
    for (int d = 1; d < 64; d <<= 1) {
        int up = __shfl_up(pre, d);
        if (lane >= d) pre += up;
    }
    const int ntl = __shfl(pre, 63);          // total live tiles
    const int chunk = (ntl + 7) >> 3;         // tiles per XCD
    const int c_xcd = blockIdx.x;             // == XCD (round-robin)
    const int qy = blockIdx.y;
    if ((qy >> 3) >= chunk) return;
    const int j = c_xcd * chunk + (qy >> 3);  // tile index
    if (j >= ntl) return;
    const int nt = qy & 7;                    // n-tile within row
    const int start_l = pre - nt_l;           // exclusive prefix
    const bool mine = (j >= start_l) && (j < start_l + nt_l);
    const unsigned long long bl = __ballot(mine);
    const int e_lane = __ffsll((long long)bl) - 1;
    const int e  = e_lane;
    const int mt = j - __shfl(start_l, e_lane);
    const int cE = __shfl(c_l, e_lane);

    const int slotbase = (e < NEXP) ? e * CAP : SHARED_BASE;
    const int m0 = mt * 128;
    const int rowsv = min(128, cE - m0);

    const unsigned short* Bte = Bt + (size_t)e * (1024 * KD);

    __shared__ unsigned short As[3][128 * 32];
    __shared__ unsigned short Bs[3][128 * 32];

    // staging: wave stages its 32 A-rows + 32 B-rows; swizzled k-seg choice
    const int rr  = lane >> 2;
    const int seg = (lane & 3) ^ ((lane >> 3) & 3);
    const int r0 = wv * 32 + rr;
    const int r1 = r0 + 16;

    int ga0 = m0 + r0, ga1 = m0 + r1;
    int ra0, ra1;
    if (GATHER) {
        ra0 = (ga0 < cE) ? tok[slotbase + ga0] : 0;  // clamp: rows discarded
        ra1 = (ga1 < cE) ? tok[slotbase + ga1] : 0;
    } else {
        ra0 = slotbase + ga0;
        ra1 = slotbase + ga1;
    }
    const unsigned short* ap0 = Ab + (size_t)ra0 * KD + seg * 8;
    const unsigned short* ap1 = Ab + (size_t)ra1 * KD + seg * 8;

    int br0, br1;
    if (SILU) {
        // local B row r: 0..31 of each wave-half -> gate col, 32..63 -> up col
        int in0 = r0 & 63, in1 = r1 & 63;
        int c0 = nt * 64 + (r0 >> 6) * 32 + (in0 & 31);
        int c1 = nt * 64 + (r1 >> 6) * 32 + (in1 & 31);
        br0 = (in0 < 32) ? c0 : 512 + c0;
        br1 = (in1 < 32) ? c1 : 512 + c1;
    } else {
        br0 = nt * 128 + r0;
        br1 = nt * 128 + r1;
    }
    const unsigned short* bp0 = Bte + (size_t)br0 * KD + seg * 8;
    const unsigned short* bp1 = Bte + (size_t)br1 * KD + seg * 8;

    const int aoff0 = (wv * 32) * 32, aoff1 = (wv * 32 + 16) * 32;

    f32x4 acc[4][4];
#pragma unroll
    for (int i = 0; i < 4; i++)
#pragma unroll
        for (int j2 = 0; j2 < 4; j2++) acc[i][j2] = (f32x4)(0.0f);

    const int mrow = lane & 15;
    const int quad = lane >> 4;
    const int wm = wv >> 1, wn = wv & 1;
    const int sw = (quad ^ ((mrow >> 1) & 3)) * 8;   // swizzled k-slot (elems)

    const int aRdOff = (wm * 64 + mrow) * 32 + sw;
    const int bRdOff = (wn * 64 + mrow) * 32 + sw;

    // prologue: stage iters 0 and 1 into buffers 0 and 1
    GLOAD_LDS16(ap0, As[0] + aoff0);
    GLOAD_LDS16(ap1, As[0] + aoff1);
    GLOAD_LDS16(bp0, Bs[0] + aoff0);
    GLOAD_LDS16(bp1, Bs[0] + aoff1);
    GLOAD_LDS16(ap0 + 32, As[1] + aoff0);
    GLOAD_LDS16(ap1 + 32, As[1] + aoff1);
    GLOAD_LDS16(bp0 + 32, Bs[1] + aoff0);
    GLOAD_LDS16(bp1 + 32, Bs[1] + aoff1);

    int p = 0;
    for (int k0 = 0; k0 < KD; k0 += 32) {
        // wait only for the OLDEST stage's 4 loads; next stage stays in flight
        if (k0 + 32 < KD) {
            asm volatile("s_waitcnt vmcnt(4) lgkmcnt(0)" ::: "memory");
        } else {
            asm volatile("s_waitcnt vmcnt(0) lgkmcnt(0)" ::: "memory");
        }
        __builtin_amdgcn_s_barrier();
        asm volatile("" ::: "memory");       // keep ds_reads/prefetch below barrier

        const int kn = k0 + 64;
        if (kn < KD) {
            int pw = p + 2; if (pw >= 3) pw -= 3;   // buffer read at iter-1: free
            GLOAD_LDS16(ap0 + kn, As[pw] + aoff0);
            GLOAD_LDS16(ap1 + kn, As[pw] + aoff1);
            GLOAD_LDS16(bp0 + kn, Bs[pw] + aoff0);
            GLOAD_LDS16(bp1 + kn, Bs[pw] + aoff1);
        }

        bf16x8 af[4], bf[4];
#pragma unroll
        for (int i = 0; i < 4; i++) {
            af[i] = *(const bf16x8*)(As[p] + aRdOff + i * 16 * 32);
            bf[i] = *(const bf16x8*)(Bs[p] + bRdOff + i * 16 * 32);
        }
#pragma unroll
        for (int mi = 0; mi < 4; mi++)
#pragma unroll
            for (int nj = 0; nj < 4; nj++)
                acc[mi][nj] = __builtin_amdgcn_mfma_f32_16x16x32_bf16(
                    af[mi], bf[nj], acc[mi][nj], 0, 0, 0);
        p++; if (p >= 3) p = 0;
        // no bottom barrier: overwrite of a buffer happens only after the
        // NEXT top barrier, whose lgkmcnt(0) guarantees all reads landed.
    }

    // C/D layout (verified m89/m91): col = lane&15, row = quad*4 + reg
    if (SILU) {
#pragma unroll
        for (int mi = 0; mi < 4; mi++)
#pragma unroll
            for (int nj = 0; nj < 2; nj++) {
                f32x4 g = acc[mi][nj];
                f32x4 u = acc[mi][nj + 2];
#pragma unroll
                for (int r = 0; r < 4; r++) {
                    int rloc = wm * 64 + mi * 16 + quad * 4 + r;
                    if (rloc < rowsv) {
                        float gv = g[r], uv = u[r];
                        float a = (gv / (1.f + __expf(-gv))) * uv;   // silu(g)*u
                        int c = nt * 64 + wn * 32 + nj * 16 + mrow;
                        Cout[(size_t)(slotbase + m0 + rloc) * ID + c] = f2bf(a);
                    }
                }
            }
    } else {
#pragma unroll
        for (int mi = 0; mi < 4; mi++)
#pragma unroll
            for (int nj = 0; nj < 4; nj++) {
                f32x4 v = acc[mi][nj];
#pragma unroll
                for (int r = 0; r < 4; r++) {
                    int rloc = wm * 64 + mi * 16 + quad * 4 + r;
                    if (rloc < rowsv) {
                        int c = nt * 128 + wn * 64 + nj * 16 + mrow;
                        Cout[(size_t)(slotbase + m0 + rloc) * HD + c] = f2bf(v[r]);
                    }
                }
            }
    }
}

// ---------------- combine: out[t] = shared + sum_k w_k * eout[slot_k] ------
__global__ __launch_bounds__(256)
void k_combine(const unsigned short* __restrict__ eout,
               const int* __restrict__ smap,
               const float* __restrict__ wgt,
               float* __restrict__ out) {
    const int t = blockIdx.x;
    const int h0 = threadIdx.x * 4;
    ushort4 q = *(const ushort4*)(eout + (size_t)(SHARED_BASE + t) * HD + h0);
    float a0 = bf2f(q.x), a1 = bf2f(q.y), a2 = bf2f(q.z), a3 = bf2f(q.w);
#pragma unroll
    for (int r = 0; r < TOPK; r++) {
        int slot = smap[t * TOPK + r];
        if (slot >= 0) {
            float w = wgt[slot];
            ushort4 e4 = *(const ushort4*)(eout + (size_t)slot * HD + h0);
            a0 += w * bf2f(e4.x); a1 += w * bf2f(e4.y);
            a2 += w * bf2f(e4.z); a3 += w * bf2f(e4.w);
        }
    }
    float4 o; o.x = a0; o.y = a1; o.z = a2; o.w = a3;
    *(float4*)(out + (size_t)t * HD + h0) = o;
}

// ---------------- launch ----------------
extern "C" void kernel_launch(void* const* d_in, const int* in_sizes, int n_in,
                              void* d_out, int out_size, void* d_ws, size_t ws_size,
                              hipStream_t stream) {
    const float* x   = (const float*)d_in[0];   // [T,H]
    const float* gw  = (const float*)d_in[1];   // [E,H]
    const float* wgu = (const float*)d_in[2];   // [E,H,2I]
    const float* wdn = (const float*)d_in[3];   // [E,I,H]
    const float* sgu = (const float*)d_in[4];   // [H,2I]
    const float* sdn = (const float*)d_in[5];   // [I,H]
    float* out = (float*)d_out;

    char* w = (char*)d_ws;
    size_t off = 0;
    int* cnt = (int*)(w + off);                       off += 256;
    unsigned short* xb     = (unsigned short*)(w + off); off += (size_t)TT * HD * 2;            // 8 MB
    unsigned short* wgup_t = (unsigned short*)(w + off); off += (size_t)33 * 1024 * 1024 * 2;   // 66 MB
    unsigned short* wdn_t  = (unsigned short*)(w + off); off += (size_t)33 * 1024 * 512 * 2;    // 33 MB
    unsigned short* act    = (unsigned short*)(w + off); off += (size_t)NSLOT * ID * 2;         // 36 MB
    unsigned short* eout   = (unsigned short*)(w + off); off += (size_t)NSLOT * HD * 2;         // 72 MB
    int*   tok    = (int*)(w + off);   off += (size_t)NSLOT * 4;
    float* wgt    = (float*)(w + off); off += (size_t)NSLOT * 4;
    int*   smap   = (int*)(w + off);   off += (size_t)TT * TOPK * 4;
    int*   choice = (int*)(w + off);   off += (size_t)TT * TOPK * 4;
    float* cw     = (float*)(w + off); off += (size_t)TT * TOPK * 4;

    // router partials (8 MB) alias eout: consumed by k_topk before GEMM2
    // produces eout — stream-ordered, no overlap.
    float* part = (float*)eout;

    // weights -> bf16, K-major ([N][K]); shared expert appended as slot 32
    k_transpose_bf16<<<dim3(16, 16, 33), 256, 0, stream>>>(wgu, sgu, wgup_t, 1024, 1024);
    k_transpose_bf16<<<dim3(16, 8, 33),  256, 0, stream>>>(wdn, sdn, wdn_t, 512, 1024);

    // router: split-K fp32 logits GEMM (+ fused x->bf16), top-4, slot scan
    k_logits<<<dim3(16, KSPLIT), 256, 0, stream>>>(x, gw, part, xb);
    k_topk<<<TT / 4, 256, 0, stream>>>(part, choice, cw, tok, wgt);
    k_assign<<<NEXP, 1024, 0, stream>>>(choice, cw, cnt, tok, wgt, smap);

    // GEMM1: gathered x @ gate_up^T, fused silu*mul -> act
    k_moe_gemm<1024, true, true><<<dim3(8, MAXTILES), 256, 0, stream>>>(xb, wgup_t, act, tok, cnt);
    // GEMM2: act @ down^T -> eout
    k_moe_gemm<512, false, false><<<dim3(8, MAXTILES), 256, 0, stream>>>(act, wdn_t, eout, tok, cnt);

    k_combine<<<TT, 256, 0, stream>>>(eout, smap, wgt, out);
}

// Round 9
// 421.610 us; speedup vs baseline: 1.0971x; 1.0083x over previous
//
#include <hip/hip_runtime.h>
#include <cstdint>
#include <cstddef>

// ---------------- problem constants ----------------
#define NEXP   32          // routed experts
#define TOPK   4
#define HD     1024        // hidden
#define ID     512         // intermediate
#define TT     4096        // tokens (B*S)
#define CAP    1024        // capacity per routed expert
#define SHARED_BASE (NEXP*CAP)        // 32768 : slot base of shared-expert rows
#define NSLOT  (NEXP*CAP + TT)        // 36864 total slot rows
#define MAXTILES 320       // grid-y: (qy>>3) up to 40 >= worst chunk 36

#define KSPLIT 16          // router split-K
#define KCH    64          // K per logits block
#define KSUB   32          // LDS sub-chunk

typedef __attribute__((ext_vector_type(4))) float f32x4;
typedef __bf16 bf16x8 __attribute__((ext_vector_type(8)));

__device__ __forceinline__ unsigned short f2bf(float f) {
    union { float f; unsigned int u; } v; v.f = f;
    unsigned int u = v.u;
    u = (u + 0x7FFFu + ((u >> 16) & 1u)) >> 16;   // RNE
    return (unsigned short)u;
}
__device__ __forceinline__ float bf2f(unsigned short s) {
    union { unsigned int u; float f; } v; v.u = ((unsigned int)s) << 16;
    return v.f;
}

#define GLOAD_LDS16(g, l)                                                     \
    __builtin_amdgcn_global_load_lds(                                         \
        (__attribute__((address_space(1))) void*)(g),                         \
        (__attribute__((address_space(3))) void*)(l), 16, 0, 0)

// ---------------- fused prep: weight transposes + logits + x->bf16 --------
// Three independent jobs in one launch (merges ramp tails, kills 2 launch
// drains): z 0..32 = gate_up transpose (expert z; z==32 -> shared),
// z 33..65 = down transpose, z == 66 = router logits + fused x convert.
// Shared mem unioned via one char buffer (38 KB = logits' xsT+gsT).
__global__ __launch_bounds__(256)
void k_prep(const float* __restrict__ wgu, const float* __restrict__ sgu,
            const float* __restrict__ wdn, const float* __restrict__ sdn,
            unsigned short* __restrict__ wgup_t, unsigned short* __restrict__ wdn_t,
            const float* __restrict__ x, const float* __restrict__ gw,
            float* __restrict__ part, unsigned short* __restrict__ xb) {
    __shared__ __align__(16) char smem[38912];
    const int z = blockIdx.z;
    const int tid = threadIdx.x;

    if (z < 66) {
        // ---- fp32 [K][N] -> bf16 [N][K] transpose ----
        const float* src; const float* srcS; unsigned short* dst; int K, N, zz;
        if (z < 33) { src = wgu; srcS = sgu; dst = wgup_t; K = 1024; N = 1024; zz = z; }
        else {
            if (blockIdx.y >= 8) return;       // dn has only 8 k-blocks
            src = wdn; srcS = sdn; dst = wdn_t; K = 512; N = 1024; zz = z - 33;
        }
        float (*ld)[65] = reinterpret_cast<float(*)[65]>(smem);  // +1 pad
        const size_t esz = (size_t)K * N;
        const float* s = (zz < NEXP) ? src + (size_t)zz * esz : srcS;
        dst += (size_t)zz * esz;
        const int n0 = blockIdx.x * 64, k0 = blockIdx.y * 64;
        const int c4 = (tid & 15) * 4;
        const int rbase = tid >> 4;        // 0..15
#pragma unroll
        for (int p = 0; p < 4; p++) {
            int row = rbase + p * 16;
            float4 v = *(const float4*)(s + (size_t)(k0 + row) * N + n0 + c4);
            ld[row][c4 + 0] = v.x; ld[row][c4 + 1] = v.y;
            ld[row][c4 + 2] = v.z; ld[row][c4 + 3] = v.w;
        }
        __syncthreads();
        const int n  = tid >> 2;           // 0..63
        const int ks = (tid & 3) * 16;     // k segment
        unsigned short tmp[16];
#pragma unroll
        for (int i = 0; i < 16; i++) tmp[i] = f2bf(ld[ks + i][n]);
        uint4 a, b;
        a.x = tmp[0] | (tmp[1] << 16);  a.y = tmp[2] | (tmp[3] << 16);
        a.z = tmp[4] | (tmp[5] << 16);  a.w = tmp[6] | (tmp[7] << 16);
        b.x = tmp[8] | (tmp[9] << 16);  b.y = tmp[10] | (tmp[11] << 16);
        b.z = tmp[12] | (tmp[13] << 16); b.w = tmp[14] | (tmp[15] << 16);
        unsigned short* op = dst + (size_t)(n0 + n) * K + k0 + ks;
        *(uint4*)op = a;
        *(uint4*)(op + 8) = b;
        return;
    }

    // ---- router logits (split-K) + fused x->bf16 convert ----
    float (*xsT)[260] = reinterpret_cast<float(*)[260]>(smem);
    float (*gsT)[36]  = reinterpret_cast<float(*)[36]>(smem + KSUB * 260 * 4);
    const int lane = tid & 63, wv = tid >> 6;
    const int tg = lane >> 2, eg = lane & 3;
    const int t0 = blockIdx.x * 256;
    const int kbase = blockIdx.y * KCH;
    const int tbase = wv * 64 + tg * 4;
    const int ebase = eg * 8;

    float acc[4][8];
#pragma unroll
    for (int j = 0; j < 4; j++)
#pragma unroll
        for (int i = 0; i < 8; i++) acc[j][i] = 0.f;

    for (int ks = 0; ks < KCH; ks += KSUB) {
        const int k0 = kbase + ks;
        if (ks > 0) __syncthreads();
#pragma unroll
        for (int p = 0; p < 8; p++) {
            int vid = p * 256 + tid;
            int t = vid >> 3, kq = (vid & 7) * 4;
            float4 v = *(const float4*)(x + (size_t)(t0 + t) * HD + k0 + kq);
            xsT[kq + 0][t] = v.x; xsT[kq + 1][t] = v.y;
            xsT[kq + 2][t] = v.z; xsT[kq + 3][t] = v.w;
            ushort4 o;
            o.x = f2bf(v.x); o.y = f2bf(v.y); o.z = f2bf(v.z); o.w = f2bf(v.w);
            *(ushort4*)(xb + (size_t)(t0 + t) * HD + k0 + kq) = o;
        }
#pragma unroll
        for (int p = 0; p < 4; p++) {
            int vid = p * 256 + tid;
            int e = vid >> 5, k = vid & 31;
            gsT[k][e] = gw[(size_t)e * HD + k0 + k];
        }
        __syncthreads();
#pragma unroll 4
        for (int k = 0; k < KSUB; k++) {
            float4 xv = *(const float4*)&xsT[k][tbase];
            float4 g0 = *(const float4*)&gsT[k][ebase];
            float4 g1 = *(const float4*)&gsT[k][ebase + 4];
            float xa[4] = {xv.x, xv.y, xv.z, xv.w};
#pragma unroll
            for (int j = 0; j < 4; j++) {
                acc[j][0] += xa[j] * g0.x; acc[j][1] += xa[j] * g0.y;
                acc[j][2] += xa[j] * g0.z; acc[j][3] += xa[j] * g0.w;
                acc[j][4] += xa[j] * g1.x; acc[j][5] += xa[j] * g1.y;
                acc[j][6] += xa[j] * g1.z; acc[j][7] += xa[j] * g1.w;
            }
        }
    }
    const size_t base = ((size_t)blockIdx.y * TT + (t0 + tbase)) * 32 + ebase;
#pragma unroll
    for (int j = 0; j < 4; j++) {
        float4 w0, w1;
        w0.x = acc[j][0]; w0.y = acc[j][1]; w0.z = acc[j][2]; w0.w = acc[j][3];
        w1.x = acc[j][4]; w1.y = acc[j][5]; w1.z = acc[j][6]; w1.w = acc[j][7];
        *(float4*)(part + base + (size_t)j * 32) = w0;
        *(float4*)(part + base + (size_t)j * 32 + 4) = w1;
    }
}

// ---------------- router part 2: reduce partials, top-4 (NO atomics) ------
__global__ __launch_bounds__(256)
void k_topk(const float* __restrict__ part,
            int* __restrict__ choice, float* __restrict__ cw,
            int* __restrict__ tok, float* __restrict__ wgt) {
    const int lane = threadIdx.x & 63, wv = threadIdx.x >> 6;
    const int t = blockIdx.x * 4 + wv;
    const int e = lane & 31;
    const int sbase = (lane >> 5) * 8;
    float v = 0.f;
#pragma unroll
    for (int s = 0; s < 8; s++)
        v += part[((size_t)(sbase + s) * TT + t) * 32 + e];
    v += __shfl_xor(v, 32);
    float sc = (lane < 32) ? v : -INFINITY;

    float lv[TOPK]; int le[TOPK];
#pragma unroll
    for (int r = 0; r < TOPK; r++) {
        float m = sc;
#pragma unroll
        for (int d = 1; d < 64; d <<= 1) m = fmaxf(m, __shfl_xor(m, d));
        unsigned long long ball = __ballot(sc == m);
        int widx = __ffsll(ball) - 1;       // lowest lane on tie = jax top_k
        lv[r] = m; le[r] = widx;
        if (lane == widx) sc = -INFINITY;
    }
    if (lane == 0) {
        float wv4[TOPK], wsum = 0.f;
#pragma unroll
        for (int r = 0; r < TOPK; r++) { wv4[r] = __expf(lv[r] - lv[0]); wsum += wv4[r]; }
#pragma unroll
        for (int r = 0; r < TOPK; r++) {
            choice[t * TOPK + r] = le[r];
            cw[t * TOPK + r] = wv4[r] / wsum;
        }
        tok[SHARED_BASE + t] = t;            // shared-expert identity slot
        wgt[SHARED_BASE + t] = 1.0f;
    }
}

// ---------------- slot assignment: token-granular ballot-scan -------------
// One thread owns one TOKEN (int4 of its 4 choices) -> 4 iterations instead
// of 16, 8 barriers instead of 32. Order: threads ascend by token, slots
// ascend within thread == global i = t*4+r order == ref's stable sort.
__global__ __launch_bounds__(1024)
void k_assign(const int* __restrict__ choice, const float* __restrict__ cw,
              int* __restrict__ cnt, int* __restrict__ tok,
              float* __restrict__ wgt, int* __restrict__ smap) {
    const int e = blockIdx.x;
    const int tid = threadIdx.x, lane = tid & 63, wv = tid >> 6;
    __shared__ int wtot[16];
    int running = 0;
    for (int it = 0; it < TT / 1024; it++) {       // 4 iterations
        const int t = it * 1024 + tid;             // token id
        const int4   c4 = *(const int4*)(choice + t * 4);
        const float4 w4 = *(const float4*)(cw + t * 4);
        unsigned m = (unsigned)(c4.x == e) | ((unsigned)(c4.y == e) << 1)
                   | ((unsigned)(c4.z == e) << 2) | ((unsigned)(c4.w == e) << 3);
        int mc = __popc(m);                        // 0..4 (almost always 0/1)
        int pre = mc;                              // inclusive wave scan
#pragma unroll
        for (int d = 1; d < 64; d <<= 1) {
            int up = __shfl_up(pre, d);
            if (lane >= d) pre += up;
        }
        if (lane == 63) wtot[wv] = pre;            // wave total
        const int wpre = pre - mc;                 // exclusive within wave
        __syncthreads();
        int woff = 0, tot = 0;
#pragma unroll
        for (int w = 0; w < 16; w++) { int c = wtot[w]; tot += c; if (w < wv) woff += c; }
        int base = running + woff + wpre;
        running += tot;
        __syncthreads();
        if (m) {
            const float wa[4] = {w4.x, w4.y, w4.z, w4.w};
            int k = 0;
#pragma unroll
            for (int r = 0; r < 4; r++) {
                if (m & (1u << r)) {
                    int pos = base + k;
                    int i = t * 4 + r;
                    if (pos < CAP) {
                        int slot = e * CAP + pos;
                        tok[slot] = t;
                        wgt[slot] = wa[r];
                        smap[i] = slot;
                    } else {
                        smap[i] = -1;              // overflow dropped (P ~ 0)
                    }
                    k++;
                }
            }
        }
    }
    if (tid == 0) cnt[e] = min(running, CAP);
}

// ---------------- grouped GEMM: 128x128 tile, BK=32 ----------------------
// 3-stage LDS pipeline, 2 K-iters of prefetch lead (T3/T4):
//   per iter: s_waitcnt vmcnt(4) (only oldest stage drained) -> raw
//   s_barrier -> issue prefetch for k+2 into buf[(it+2)%3] -> ds_read + MFMA.
// 48KB LDS + ~140 regs/wave -> 3 blocks/CU co-resident (the occupancy that
// R6/R7 experiments proved dominant: 256x256 (1 blk/CU) = 102us, BK=64
// (2 blk/CU) = 83us, this = 78.6us).
// In-kernel tile table (33-lane prefix scan over cnt); XCD map (T1):
// grid (8, MAXTILES), linear id = bx + 8*by -> XCD == bx; XCD c owns a
// contiguous chunk of live tiles, 8 nt-blocks of one tile adjacent.
// LDS k-seg XOR swizzle (slot s of row r holds seg s^((r>>1)&3)): 0 conflicts.
template <int KD, bool GATHER, bool SILU>
__global__ __launch_bounds__(256)
void k_moe_gemm(const unsigned short* __restrict__ Ab,
                const unsigned short* __restrict__ Bt,
                unsigned short* __restrict__ Cout,
                const int* __restrict__ tok,
                const int* __restrict__ cnt) {
    const int tid  = threadIdx.x;
    const int lane = tid & 63;
    const int wv   = tid >> 6;

    // ---- in-kernel tile table ----
    int c_l = (lane < NEXP) ? min(cnt[lane], CAP) : ((lane == NEXP) ? TT : 0);
    int nt_l = (c_l + 127) >> 7;              // 128-row m-tiles of expert 'lane'
    int pre = nt_l;
#pragma unroll
    for (int d = 1; d < 64; d <<= 1) {
        int up = __shfl_up(pre, d);
        if (lane >= d) pre += up;
    }
    const int ntl = __shfl(pre, 63);          // total live tiles
    const int chunk = (ntl + 7) >> 3;         // tiles per XCD
    const int c_xcd = blockIdx.x;             // == XCD (round-robin)
    const int qy = blockIdx.y;
    if ((qy >> 3) >= chunk) return;
    const int j = c_xcd * chunk + (qy >> 3);  // tile index
    if (j >= ntl) return;
    const int nt = qy & 7;                    // n-tile within row
    const int start_l = pre - nt_l;           // exclusive prefix
    const bool mine = (j >= start_l) && (j < start_l + nt_l);
    const unsigned long long bl = __ballot(mine);
    const int e_lane = __ffsll((long long)bl) - 1;
    const int e  = e_lane;
    const int mt = j - __shfl(start_l, e_lane);
    const int cE = __shfl(c_l, e_lane);

    const int slotbase = (e < NEXP) ? e * CAP : SHARED_BASE;
    const int m0 = mt * 128;
    const int rowsv = min(128, cE - m0);

    const unsigned short* Bte = Bt + (size_t)e * (1024 * KD);

    __shared__ unsigned short As[3][128 * 32];
    __shared__ unsigned short Bs[3][128 * 32];

    // staging: wave stages its 32 A-rows + 32 B-rows; swizzled k-seg choice
    const int rr  = lane >> 2;
    const int seg = (lane & 3) ^ ((lane >> 3) & 3);
    const int r0 = wv * 32 + rr;
    const int r1 = r0 + 16;

    int ga0 = m0 + r0, ga1 = m0 + r1;
    int ra0, ra1;
    if (GATHER) {
        ra0 = (ga0 < cE) ? tok[slotbase + ga0] : 0;  // clamp: rows discarded
        ra1 = (ga1 < cE) ? tok[slotbase + ga1] : 0;
    } else {
        ra0 = slotbase + ga0;
        ra1 = slotbase + ga1;
    }
    const unsigned short* ap0 = Ab + (size_t)ra0 * KD + seg * 8;
    const unsigned short* ap1 = Ab + (size_t)ra1 * KD + seg * 8;

    int br0, br1;
    if (SILU) {
        // local B row r: 0..31 of each wave-half -> gate col, 32..63 -> up col
        int in0 = r0 & 63, in1 = r1 & 63;
        int c0 = nt * 64 + (r0 >> 6) * 32 + (in0 & 31);
        int c1 = nt * 64 + (r1 >> 6) * 32 + (in1 & 31);
        br0 = (in0 < 32) ? c0 : 512 + c0;
        br1 = (in1 < 32) ? c1 : 512 + c1;
    } else {
        br0 = nt * 128 + r0;
        br1 = nt * 128 + r1;
    }
    const unsigned short* bp0 = Bte + (size_t)br0 * KD + seg * 8;
    const unsigned short* bp1 = Bte + (size_t)br1 * KD + seg * 8;

    const int aoff0 = (wv * 32) * 32, aoff1 = (wv * 32 + 16) * 32;

    f32x4 acc[4][4];
#pragma unroll
    for (int i = 0; i < 4; i++)
#pragma unroll
        for (int j2 = 0; j2 < 4; j2++) acc[i][j2] = (f32x4)(0.0f);

    const int mrow = lane & 15;
    const int quad = lane >> 4;
    const int wm = wv >> 1, wn = wv & 1;
    const int sw = (quad ^ ((mrow >> 1) & 3)) * 8;   // swizzled k-slot (elems)

    const int aRdOff = (wm * 64 + mrow) * 32 + sw;
    const int bRdOff = (wn * 64 + mrow) * 32 + sw;

    // prologue: stage iters 0 and 1 into buffers 0 and 1
    GLOAD_LDS16(ap0, As[0] + aoff0);
    GLOAD_LDS16(ap1, As[0] + aoff1);
    GLOAD_LDS16(bp0, Bs[0] + aoff0);
    GLOAD_LDS16(bp1, Bs[0] + aoff1);
    GLOAD_LDS16(ap0 + 32, As[1] + aoff0);
    GLOAD_LDS16(ap1 + 32, As[1] + aoff1);
    GLOAD_LDS16(bp0 + 32, Bs[1] + aoff0);
    GLOAD_LDS16(bp1 + 32, Bs[1] + aoff1);

    int p = 0;
    for (int k0 = 0; k0 < KD; k0 += 32) {
        // wait only for the OLDEST stage's 4 loads; next stage stays in flight
        if (k0 + 32 < KD) {
            asm volatile("s_waitcnt vmcnt(4) lgkmcnt(0)" ::: "memory");
        } else {
            asm volatile("s_waitcnt vmcnt(0) lgkmcnt(0)" ::: "memory");
        }
        __builtin_amdgcn_s_barrier();
        asm volatile("" ::: "memory");       // keep ds_reads/prefetch below barrier

        const int kn = k0 + 64;
        if (kn < KD) {
            int pw = p + 2; if (pw >= 3) pw -= 3;   // buffer read at iter-1: free
            GLOAD_LDS16(ap0 + kn, As[pw] + aoff0);
            GLOAD_LDS16(ap1 + kn, As[pw] + aoff1);
            GLOAD_LDS16(bp0 + kn, Bs[pw] + aoff0);
            GLOAD_LDS16(bp1 + kn, Bs[pw] + aoff1);
        }

        bf16x8 af[4], bf[4];
#pragma unroll
        for (int i = 0; i < 4; i++) {
            af[i] = *(const bf16x8*)(As[p] + aRdOff + i * 16 * 32);
            bf[i] = *(const bf16x8*)(Bs[p] + bRdOff + i * 16 * 32);
        }
#pragma unroll
        for (int mi = 0; mi < 4; mi++)
#pragma unroll
            for (int nj = 0; nj < 4; nj++)
                acc[mi][nj] = __builtin_amdgcn_mfma_f32_16x16x32_bf16(
                    af[mi], bf[nj], acc[mi][nj], 0, 0, 0);
        p++; if (p >= 3) p = 0;
        // no bottom barrier: overwrite of a buffer happens only after the
        // NEXT top barrier, whose lgkmcnt(0) guarantees all reads landed.
    }

    // C/D layout (verified m89/m91): col = lane&15, row = quad*4 + reg
    if (SILU) {
#pragma unroll
        for (int mi = 0; mi < 4; mi++)
#pragma unroll
            for (int nj = 0; nj < 2; nj++) {
                f32x4 g = acc[mi][nj];
                f32x4 u = acc[mi][nj + 2];
#pragma unroll
                for (int r = 0; r < 4; r++) {
                    int rloc = wm * 64 + mi * 16 + quad * 4 + r;
                    if (rloc < rowsv) {
                        float gv = g[r], uv = u[r];
                        float a = (gv / (1.f + __expf(-gv))) * uv;   // silu(g)*u
                        int c = nt * 64 + wn * 32 + nj * 16 + mrow;
                        Cout[(size_t)(slotbase + m0 + rloc) * ID + c] = f2bf(a);
                    }
                }
            }
    } else {
#pragma unroll
        for (int mi = 0; mi < 4; mi++)
#pragma unroll
            for (int nj = 0; nj < 4; nj++) {
                f32x4 v = acc[mi][nj];
#pragma unroll
                for (int r = 0; r < 4; r++) {
                    int rloc = wm * 64 + mi * 16 + quad * 4 + r;
                    if (rloc < rowsv) {
                        int c = nt * 128 + wn * 64 + nj * 16 + mrow;
                        Cout[(size_t)(slotbase + m0 + rloc) * HD + c] = f2bf(v[r]);
                    }
                }
            }
    }
}

// ---------------- combine: out[t] = shared + sum_k w_k * eout[slot_k] ------
__global__ __launch_bounds__(256)
void k_combine(const unsigned short* __restrict__ eout,
               const int* __restrict__ smap,
               const float* __restrict__ wgt,
               float* __restrict__ out) {
    const int t = blockIdx.x;
    const int h0 = threadIdx.x * 4;
    ushort4 q = *(const ushort4*)(eout + (size_t)(SHARED_BASE + t) * HD + h0);
    float a0 = bf2f(q.x), a1 = bf2f(q.y), a2 = bf2f(q.z), a3 = bf2f(q.w);
#pragma unroll
    for (int r = 0; r < TOPK; r++) {
        int slot = smap[t * TOPK + r];
        if (slot >= 0) {
            float w = wgt[slot];
            ushort4 e4 = *(const ushort4*)(eout + (size_t)slot * HD + h0);
            a0 += w * bf2f(e4.x); a1 += w * bf2f(e4.y);
            a2 += w * bf2f(e4.z); a3 += w * bf2f(e4.w);
        }
    }
    float4 o; o.x = a0; o.y = a1; o.z = a2; o.w = a3;
    *(float4*)(out + (size_t)t * HD + h0) = o;
}

// ---------------- launch ----------------
// Workspace aliasing (dependency-audited):
//   part (8 MB)  aliases act    : part written by prep, consumed by topk,
//                                 act written only later by GEMM1.
//   eout (72 MB) aliases xb+wgup_t (74 MB): both dead after GEMM1; eout
//                                 written by GEMM2, read by combine.
// Used workspace: 256 + 8M + 66M + 33M + 36M + ~1.2M ~= 145 MB (was 216).
extern "C" void kernel_launch(void* const* d_in, const int* in_sizes, int n_in,
                              void* d_out, int out_size, void* d_ws, size_t ws_size,
                              hipStream_t stream) {
    const float* x   = (const float*)d_in[0];   // [T,H]
    const float* gw  = (const float*)d_in[1];   // [E,H]
    const float* wgu = (const float*)d_in[2];   // [E,H,2I]
    const float* wdn = (const float*)d_in[3];   // [E,I,H]
    const float* sgu = (const float*)d_in[4];   // [H,2I]
    const float* sdn = (const float*)d_in[5];   // [I,H]
    float* out = (float*)d_out;

    char* w = (char*)d_ws;
    size_t off = 0;
    int* cnt = (int*)(w + off);                       off += 256;
    unsigned short* xb     = (unsigned short*)(w + off); off += (size_t)TT * HD * 2;            // 8 MB
    unsigned short* wgup_t = (unsigned short*)(w + off); off += (size_t)33 * 1024 * 1024 * 2;   // 66 MB
    unsigned short* wdn_t  = (unsigned short*)(w + off); off += (size_t)33 * 1024 * 512 * 2;    // 33 MB
    unsigned short* act    = (unsigned short*)(w + off); off += (size_t)NSLOT * ID * 2;         // 36 MB
    int*   tok    = (int*)(w + off);   off += (size_t)NSLOT * 4;
    float* wgt    = (float*)(w + off); off += (size_t)NSLOT * 4;
    int*   smap   = (int*)(w + off);   off += (size_t)TT * TOPK * 4;
    int*   choice = (int*)(w + off);   off += (size_t)TT * TOPK * 4;
    float* cw     = (float*)(w + off); off += (size_t)TT * TOPK * 4;

    float* part = (float*)act;                        // alias: dead before GEMM1
    unsigned short* eout = xb;                        // alias: xb+wgup_t dead after GEMM1

    // prep: both weight transposes + logits + x->bf16, one launch
    k_prep<<<dim3(16, 16, 67), 256, 0, stream>>>(wgu, sgu, wdn, sdn,
                                                 wgup_t, wdn_t, x, gw, part, xb);
    k_topk<<<TT / 4, 256, 0, stream>>>(part, choice, cw, tok, wgt);
    k_assign<<<NEXP, 1024, 0, stream>>>(choice, cw, cnt, tok, wgt, smap);

    // GEMM1: gathered x @ gate_up^T, fused silu*mul -> act
    k_moe_gemm<1024, true, true><<<dim3(8, MAXTILES), 256, 0, stream>>>(xb, wgup_t, act, tok, cnt);
    // GEMM2: act @ down^T -> eout
    k_moe_gemm<512, false, false><<<dim3(8, MAXTILES), 256, 0, stream>>>(act, wdn_t, eout, tok, cnt);

    k_combine<<<TT, 256, 0, stream>>>(eout, smap, wgt, out);
}

// Round 10
// 417.513 us; speedup vs baseline: 1.1078x; 1.0098x over previous
//
#include <hip/hip_runtime.h>
#include <cstdint>
#include <cstddef>

// ---------------- problem constants ----------------
#define NEXP   32          // routed experts
#define TOPK   4
#define HD     1024        // hidden
#define ID     512         // intermediate
#define TT     4096        // tokens (B*S)
#define CAP    1024        // capacity per routed expert
#define SHARED_BASE (NEXP*CAP)        // 32768 : slot base of shared-expert rows
#define NSLOT  (NEXP*CAP + TT)        // 36864 total slot rows
#define MAXTILES 320       // grid-y: (qy>>3) up to 40 >= worst chunk 36

#define KSPLIT 16          // router split-K
#define KCH    64          // K per logits block
#define KSUB   16          // LDS sub-chunk (16 -> 18.9 KB union -> 8 blk/CU)

typedef __attribute__((ext_vector_type(4))) float f32x4;
typedef __bf16 bf16x8 __attribute__((ext_vector_type(8)));

__device__ __forceinline__ unsigned short f2bf(float f) {
    union { float f; unsigned int u; } v; v.f = f;
    unsigned int u = v.u;
    u = (u + 0x7FFFu + ((u >> 16) & 1u)) >> 16;   // RNE
    return (unsigned short)u;
}
__device__ __forceinline__ float bf2f(unsigned short s) {
    union { unsigned int u; float f; } v; v.u = ((unsigned int)s) << 16;
    return v.f;
}

#define GLOAD_LDS16(g, l)                                                     \
    __builtin_amdgcn_global_load_lds(                                         \
        (__attribute__((address_space(1))) void*)(g),                         \
        (__attribute__((address_space(3))) void*)(l), 16, 0, 0)

// ---------------- fused prep: weight transposes + logits + x->bf16 --------
// z 0..32 = gate_up transpose (expert z; z==32 -> shared), z 33..65 = down
// transpose, z == 66 = router logits + fused x convert.
// LDS union is TRANSPOSE-sized (18944 B): logits uses KSUB=16 so its
// xsT[16][260]+gsT[16][36] fits in the same 18.9 KB as the 64x65 transpose
// tile -> 8 blocks/CU for every prep block (R9's 38.9 KB union capped the
// BW-bound transposes at 4 blocks/CU -> 2 TB/s, 25% HBM).
__global__ __launch_bounds__(256)
void k_prep(const float* __restrict__ wgu, const float* __restrict__ sgu,
            const float* __restrict__ wdn, const float* __restrict__ sdn,
            unsigned short* __restrict__ wgup_t, unsigned short* __restrict__ wdn_t,
            const float* __restrict__ x, const float* __restrict__ gw,
            float* __restrict__ part, unsigned short* __restrict__ xb) {
    __shared__ __align__(16) char smem[18944];
    const int z = blockIdx.z;
    const int tid = threadIdx.x;

    if (z < 66) {
        // ---- fp32 [K][N] -> bf16 [N][K] transpose ----
        const float* src; const float* srcS; unsigned short* dst; int K, N, zz;
        if (z < 33) { src = wgu; srcS = sgu; dst = wgup_t; K = 1024; N = 1024; zz = z; }
        else {
            if (blockIdx.y >= 8) return;       // dn has only 8 k-blocks
            src = wdn; srcS = sdn; dst = wdn_t; K = 512; N = 1024; zz = z - 33;
        }
        float (*ld)[65] = reinterpret_cast<float(*)[65]>(smem);  // +1 pad
        const size_t esz = (size_t)K * N;
        const float* s = (zz < NEXP) ? src + (size_t)zz * esz : srcS;
        dst += (size_t)zz * esz;
        const int n0 = blockIdx.x * 64, k0 = blockIdx.y * 64;
        const int c4 = (tid & 15) * 4;
        const int rbase = tid >> 4;        // 0..15
#pragma unroll
        for (int p = 0; p < 4; p++) {
            int row = rbase + p * 16;
            float4 v = *(const float4*)(s + (size_t)(k0 + row) * N + n0 + c4);
            ld[row][c4 + 0] = v.x; ld[row][c4 + 1] = v.y;
            ld[row][c4 + 2] = v.z; ld[row][c4 + 3] = v.w;
        }
        __syncthreads();
        const int n  = tid >> 2;           // 0..63
        const int ks = (tid & 3) * 16;     // k segment
        unsigned short tmp[16];
#pragma unroll
        for (int i = 0; i < 16; i++) tmp[i] = f2bf(ld[ks + i][n]);
        uint4 a, b;
        a.x = tmp[0] | (tmp[1] << 16);  a.y = tmp[2] | (tmp[3] << 16);
        a.z = tmp[4] | (tmp[5] << 16);  a.w = tmp[6] | (tmp[7] << 16);
        b.x = tmp[8] | (tmp[9] << 16);  b.y = tmp[10] | (tmp[11] << 16);
        b.z = tmp[12] | (tmp[13] << 16); b.w = tmp[14] | (tmp[15] << 16);
        unsigned short* op = dst + (size_t)(n0 + n) * K + k0 + ks;
        *(uint4*)op = a;
        *(uint4*)(op + 8) = b;
        return;
    }

    // ---- router logits (split-K, KSUB=16) + fused x->bf16 convert ----
    float (*xsT)[260] = reinterpret_cast<float(*)[260]>(smem);          // 16.6 KB
    float (*gsT)[36]  = reinterpret_cast<float(*)[36]>(smem + KSUB * 260 * 4);
    const int lane = tid & 63, wv = tid >> 6;
    const int tg = lane >> 2, eg = lane & 3;
    const int t0 = blockIdx.x * 256;
    const int kbase = blockIdx.y * KCH;
    const int tbase = wv * 64 + tg * 4;
    const int ebase = eg * 8;

    float acc[4][8];
#pragma unroll
    for (int j = 0; j < 4; j++)
#pragma unroll
        for (int i = 0; i < 8; i++) acc[j][i] = 0.f;

    for (int ks = 0; ks < KCH; ks += KSUB) {
        const int k0 = kbase + ks;
        if (ks > 0) __syncthreads();
        // stage x sub-chunk [256 t][16 k] (+ bf16 copy); 2-way banks (free)
#pragma unroll
        for (int p = 0; p < 4; p++) {
            int vid = p * 256 + tid;
            int t = vid >> 2, kq = (vid & 3) * 4;
            float4 v = *(const float4*)(x + (size_t)(t0 + t) * HD + k0 + kq);
            xsT[kq + 0][t] = v.x; xsT[kq + 1][t] = v.y;
            xsT[kq + 2][t] = v.z; xsT[kq + 3][t] = v.w;
            ushort4 o;
            o.x = f2bf(v.x); o.y = f2bf(v.y); o.z = f2bf(v.z); o.w = f2bf(v.w);
            *(ushort4*)(xb + (size_t)(t0 + t) * HD + k0 + kq) = o;
        }
#pragma unroll
        for (int p = 0; p < 2; p++) {
            int vid = p * 256 + tid;
            int e = vid >> 4, k = vid & 15;
            gsT[k][e] = gw[(size_t)e * HD + k0 + k];
        }
        __syncthreads();
#pragma unroll 4
        for (int k = 0; k < KSUB; k++) {
            float4 xv = *(const float4*)&xsT[k][tbase];
            float4 g0 = *(const float4*)&gsT[k][ebase];
            float4 g1 = *(const float4*)&gsT[k][ebase + 4];
            float xa[4] = {xv.x, xv.y, xv.z, xv.w};
#pragma unroll
            for (int j = 0; j < 4; j++) {
                acc[j][0] += xa[j] * g0.x; acc[j][1] += xa[j] * g0.y;
                acc[j][2] += xa[j] * g0.z; acc[j][3] += xa[j] * g0.w;
                acc[j][4] += xa[j] * g1.x; acc[j][5] += xa[j] * g1.y;
                acc[j][6] += xa[j] * g1.z; acc[j][7] += xa[j] * g1.w;
            }
        }
    }
    const size_t base = ((size_t)blockIdx.y * TT + (t0 + tbase)) * 32 + ebase;
#pragma unroll
    for (int j = 0; j < 4; j++) {
        float4 w0, w1;
        w0.x = acc[j][0]; w0.y = acc[j][1]; w0.z = acc[j][2]; w0.w = acc[j][3];
        w1.x = acc[j][4]; w1.y = acc[j][5]; w1.z = acc[j][6]; w1.w = acc[j][7];
        *(float4*)(part + base + (size_t)j * 32) = w0;
        *(float4*)(part + base + (size_t)j * 32 + 4) = w1;
    }
}

// ---------------- router part 2: reduce partials, top-4 (NO atomics) ------
__global__ __launch_bounds__(256)
void k_topk(const float* __restrict__ part,
            int* __restrict__ choice, float* __restrict__ cw,
            int* __restrict__ tok, float* __restrict__ wgt) {
    const int lane = threadIdx.x & 63, wv = threadIdx.x >> 6;
    const int t = blockIdx.x * 4 + wv;
    const int e = lane & 31;
    const int sbase = (lane >> 5) * 8;
    float v = 0.f;
#pragma unroll
    for (int s = 0; s < 8; s++)
        v += part[((size_t)(sbase + s) * TT + t) * 32 + e];
    v += __shfl_xor(v, 32);
    float sc = (lane < 32) ? v : -INFINITY;

    float lv[TOPK]; int le[TOPK];
#pragma unroll
    for (int r = 0; r < TOPK; r++) {
        float m = sc;
#pragma unroll
        for (int d = 1; d < 64; d <<= 1) m = fmaxf(m, __shfl_xor(m, d));
        unsigned long long ball = __ballot(sc == m);
        int widx = __ffsll(ball) - 1;       // lowest lane on tie = jax top_k
        lv[r] = m; le[r] = widx;
        if (lane == widx) sc = -INFINITY;
    }
    if (lane == 0) {
        float wv4[TOPK], wsum = 0.f;
#pragma unroll
        for (int r = 0; r < TOPK; r++) { wv4[r] = __expf(lv[r] - lv[0]); wsum += wv4[r]; }
#pragma unroll
        for (int r = 0; r < TOPK; r++) {
            choice[t * TOPK + r] = le[r];
            cw[t * TOPK + r] = wv4[r] / wsum;
        }
        tok[SHARED_BASE + t] = t;            // shared-expert identity slot
        wgt[SHARED_BASE + t] = 1.0f;
    }
}

// ---------------- slot assignment: token-granular ballot-scan -------------
// One thread owns one TOKEN (int4 of its 4 choices) -> 4 iterations instead
// of 16, 8 barriers instead of 32. Order: threads ascend by token, slots
// ascend within thread == global i = t*4+r order == ref's stable sort.
__global__ __launch_bounds__(1024)
void k_assign(const int* __restrict__ choice, const float* __restrict__ cw,
              int* __restrict__ cnt, int* __restrict__ tok,
              float* __restrict__ wgt, int* __restrict__ smap) {
    const int e = blockIdx.x;
    const int tid = threadIdx.x, lane = tid & 63, wv = tid >> 6;
    __shared__ int wtot[16];
    int running = 0;
    for (int it = 0; it < TT / 1024; it++) {       // 4 iterations
        const int t = it * 1024 + tid;             // token id
        const int4   c4 = *(const int4*)(choice + t * 4);
        const float4 w4 = *(const float4*)(cw + t * 4);
        unsigned m = (unsigned)(c4.x == e) | ((unsigned)(c4.y == e) << 1)
                   | ((unsigned)(c4.z == e) << 2) | ((unsigned)(c4.w == e) << 3);
        int mc = __popc(m);                        // 0..4 (almost always 0/1)
        int pre = mc;                              // inclusive wave scan
#pragma unroll
        for (int d = 1; d < 64; d <<= 1) {
            int up = __shfl_up(pre, d);
            if (lane >= d) pre += up;
        }
        if (lane == 63) wtot[wv] = pre;            // wave total
        const int wpre = pre - mc;                 // exclusive within wave
        __syncthreads();
        int woff = 0, tot = 0;
#pragma unroll
        for (int w = 0; w < 16; w++) { int c = wtot[w]; tot += c; if (w < wv) woff += c; }
        int base = running + woff + wpre;
        running += tot;
        __syncthreads();
        if (m) {
            const float wa[4] = {w4.x, w4.y, w4.z, w4.w};
            int k = 0;
#pragma unroll
            for (int r = 0; r < 4; r++) {
                if (m & (1u << r)) {
                    int pos = base + k;
                    int i = t * 4 + r;
                    if (pos < CAP) {
                        int slot = e * CAP + pos;
                        tok[slot] = t;
                        wgt[slot] = wa[r];
                        smap[i] = slot;
                    } else {
                        smap[i] = -1;              // overflow dropped (P ~ 0)
                    }
                    k++;
                }
            }
        }
    }
    if (tid == 0) cnt[e] = min(running, CAP);
}

// ---------------- grouped GEMM: 128x128 tile, BK=32 ----------------------
// 3-stage LDS pipeline, 2 K-iters of prefetch lead (T3/T4):
//   per iter: s_waitcnt vmcnt(4) (only oldest stage drained) -> raw
//   s_barrier -> issue prefetch for k+2 into buf[(it+2)%3] -> ds_read + MFMA.
// 48KB LDS + ~140 regs/wave -> 3 blocks/CU co-resident (the occupancy that
// R6/R7 experiments proved dominant: 256x256 (1 blk/CU) = 102us, BK=64
// (2 blk/CU) = 83us, this = 78.6us).
// In-kernel tile table (33-lane prefix scan over cnt); XCD map (T1):
// grid (8, MAXTILES), linear id = bx + 8*by -> XCD == bx; XCD c owns a
// contiguous chunk of live tiles, 8 nt-blocks of one tile adjacent.
// LDS k-seg XOR swizzle (slot s of row r holds seg s^((r>>1)&3)): 0 conflicts.
template <int KD, bool GATHER, bool SILU>
__global__ __launch_bounds__(256)
void k_moe_gemm(const unsigned short* __restrict__ Ab,
                const unsigned short* __restrict__ Bt,
                unsigned short* __restrict__ Cout,
                const int* __restrict__ tok,
                const int* __restrict__ cnt) {
    const int tid  = threadIdx.x;
    const int lane = tid & 63;
    const int wv   = tid >> 6;

    // ---- in-kernel tile table ----
    int c_l = (lane < NEXP) ? min(cnt[lane], CAP) : ((lane == NEXP) ? TT : 0);
    int nt_l = (c_l + 127) >> 7;              // 128-row m-tiles of expert 'lane'
    int pre = nt_l;
#pragma unroll
    for (int d = 1; d < 64; d <<= 1) {
        int up = __shfl_up(pre, d);
        if (lane >= d) pre += up;
    }
    const int ntl = __shfl(pre, 63);          // total live tiles
    const int chunk = (ntl + 7) >> 3;         // tiles per XCD
    const int c_xcd = blockIdx.x;             // == XCD (round-robin)
    const int qy = blockIdx.y;
    if ((qy >> 3) >= chunk) return;
    const int j = c_xcd * chunk + (qy >> 3);  // tile index
    if (j >= ntl) return;
    const int nt = qy & 7;                    // n-tile within row
    const int start_l = pre - nt_l;           // exclusive prefix
    const bool mine = (j >= start_l) && (j < start_l + nt_l);
    const unsigned long long bl = __ballot(mine);
    const int e_lane = __ffsll((long long)bl) - 1;
    const int e  = e_lane;
    const int mt = j - __shfl(start_l, e_lane);
    const int cE = __shfl(c_l, e_lane);

    const int slotbase = (e < NEXP) ? e * CAP : SHARED_BASE;
    const int m0 = mt * 128;
    const int rowsv = min(128, cE - m0);

    const unsigned short* Bte = Bt + (size_t)e * (1024 * KD);

    __shared__ unsigned short As[3][128 * 32];
    __shared__ unsigned short Bs[3][128 * 32];

    // staging: wave stages its 32 A-rows + 32 B-rows; swizzled k-seg choice
    const int rr  = lane >> 2;
    const int seg = (lane & 3) ^ ((lane >> 3) & 3);
    const int r0 = wv * 32 + rr;
    const int r1 = r0 + 16;

    int ga0 = m0 + r0, ga1 = m0 + r1;
    int ra0, ra1;
    if (GATHER) {
        ra0 = (ga0 < cE) ? tok[slotbase + ga0] : 0;  // clamp: rows discarded
        ra1 = (ga1 < cE) ? tok[slotbase + ga1] : 0;
    } else {
        ra0 = slotbase + ga0;
        ra1 = slotbase + ga1;
    }
    const unsigned short* ap0 = Ab + (size_t)ra0 * KD + seg * 8;
    const unsigned short* ap1 = Ab + (size_t)ra1 * KD + seg * 8;

    int br0, br1;
    if (SILU) {
        // local B row r: 0..31 of each wave-half -> gate col, 32..63 -> up col
        int in0 = r0 & 63, in1 = r1 & 63;
        int c0 = nt * 64 + (r0 >> 6) * 32 + (in0 & 31);
        int c1 = nt * 64 + (r1 >> 6) * 32 + (in1 & 31);
        br0 = (in0 < 32) ? c0 : 512 + c0;
        br1 = (in1 < 32) ? c1 : 512 + c1;
    } else {
        br0 = nt * 128 + r0;
        br1 = nt * 128 + r1;
    }
    const unsigned short* bp0 = Bte + (size_t)br0 * KD + seg * 8;
    const unsigned short* bp1 = Bte + (size_t)br1 * KD + seg * 8;

    const int aoff0 = (wv * 32) * 32, aoff1 = (wv * 32 + 16) * 32;

    f32x4 acc[4][4];
#pragma unroll
    for (int i = 0; i < 4; i++)
#pragma unroll
        for (int j2 = 0; j2 < 4; j2++) acc[i][j2] = (f32x4)(0.0f);

    const int mrow = lane & 15;
    const int quad = lane >> 4;
    const int wm = wv >> 1, wn = wv & 1;
    const int sw = (quad ^ ((mrow >> 1) & 3)) * 8;   // swizzled k-slot (elems)

    const int aRdOff = (wm * 64 + mrow) * 32 + sw;
    const int bRdOff = (wn * 64 + mrow) * 32 + sw;

    // prologue: stage iters 0 and 1 into buffers 0 and 1
    GLOAD_LDS16(ap0, As[0] + aoff0);
    GLOAD_LDS16(ap1, As[0] + aoff1);
    GLOAD_LDS16(bp0, Bs[0] + aoff0);
    GLOAD_LDS16(bp1, Bs[0] + aoff1);
    GLOAD_LDS16(ap0 + 32, As[1] + aoff0);
    GLOAD_LDS16(ap1 + 32, As[1] + aoff1);
    GLOAD_LDS16(bp0 + 32, Bs[1] + aoff0);
    GLOAD_LDS16(bp1 + 32, Bs[1] + aoff1);

    int p = 0;
    for (int k0 = 0; k0 < KD; k0 += 32) {
        // wait only for the OLDEST stage's 4 loads; next stage stays in flight
        if (k0 + 32 < KD) {
            asm volatile("s_waitcnt vmcnt(4) lgkmcnt(0)" ::: "memory");
        } else {
            asm volatile("s_waitcnt vmcnt(0) lgkmcnt(0)" ::: "memory");
        }
        __builtin_amdgcn_s_barrier();
        asm volatile("" ::: "memory");       // keep ds_reads/prefetch below barrier

        const int kn = k0 + 64;
        if (kn < KD) {
            int pw = p + 2; if (pw >= 3) pw -= 3;   // buffer read at iter-1: free
            GLOAD_LDS16(ap0 + kn, As[pw] + aoff0);
            GLOAD_LDS16(ap1 + kn, As[pw] + aoff1);
            GLOAD_LDS16(bp0 + kn, Bs[pw] + aoff0);
            GLOAD_LDS16(bp1 + kn, Bs[pw] + aoff1);
        }

        bf16x8 af[4], bf[4];
#pragma unroll
        for (int i = 0; i < 4; i++) {
            af[i] = *(const bf16x8*)(As[p] + aRdOff + i * 16 * 32);
            bf[i] = *(const bf16x8*)(Bs[p] + bRdOff + i * 16 * 32);
        }
#pragma unroll
        for (int mi = 0; mi < 4; mi++)
#pragma unroll
            for (int nj = 0; nj < 4; nj++)
                acc[mi][nj] = __builtin_amdgcn_mfma_f32_16x16x32_bf16(
                    af[mi], bf[nj], acc[mi][nj], 0, 0, 0);
        p++; if (p >= 3) p = 0;
        // no bottom barrier: overwrite of a buffer happens only after the
        // NEXT top barrier, whose lgkmcnt(0) guarantees all reads landed.
    }

    // C/D layout (verified m89/m91): col = lane&15, row = quad*4 + reg
    if (SILU) {
#pragma unroll
        for (int mi = 0; mi < 4; mi++)
#pragma unroll
            for (int nj = 0; nj < 2; nj++) {
                f32x4 g = acc[mi][nj];
                f32x4 u = acc[mi][nj + 2];
#pragma unroll
                for (int r = 0; r < 4; r++) {
                    int rloc = wm * 64 + mi * 16 + quad * 4 + r;
                    if (rloc < rowsv) {
                        float gv = g[r], uv = u[r];
                        float a = (gv / (1.f + __expf(-gv))) * uv;   // silu(g)*u
                        int c = nt * 64 + wn * 32 + nj * 16 + mrow;
                        Cout[(size_t)(slotbase + m0 + rloc) * ID + c] = f2bf(a);
                    }
                }
            }
    } else {
#pragma unroll
        for (int mi = 0; mi < 4; mi++)
#pragma unroll
            for (int nj = 0; nj < 4; nj++) {
                f32x4 v = acc[mi][nj];
#pragma unroll
                for (int r = 0; r < 4; r++) {
                    int rloc = wm * 64 + mi * 16 + quad * 4 + r;
                    if (rloc < rowsv) {
                        int c = nt * 128 + wn * 64 + nj * 16 + mrow;
                        Cout[(size_t)(slotbase + m0 + rloc) * HD + c] = f2bf(v[r]);
                    }
                }
            }
    }
}

// ---------------- combine: out[t] = shared + sum_k w_k * eout[slot_k] ------
__global__ __launch_bounds__(256)
void k_combine(const unsigned short* __restrict__ eout,
               const int* __restrict__ smap,
               const float* __restrict__ wgt,
               float* __restrict__ out) {
    const int t = blockIdx.x;
    const int h0 = threadIdx.x * 4;
    ushort4 q = *(const ushort4*)(eout + (size_t)(SHARED_BASE + t) * HD + h0);
    float a0 = bf2f(q.x), a1 = bf2f(q.y), a2 = bf2f(q.z), a3 = bf2f(q.w);
#pragma unroll
    for (int r = 0; r < TOPK; r++) {
        int slot = smap[t * TOPK + r];
        if (slot >= 0) {
            float w = wgt[slot];
            ushort4 e4 = *(const ushort4*)(eout + (size_t)slot * HD + h0);
            a0 += w * bf2f(e4.x); a1 += w * bf2f(e4.y);
            a2 += w * bf2f(e4.z); a3 += w * bf2f(e4.w);
        }
    }
    float4 o; o.x = a0; o.y = a1; o.z = a2; o.w = a3;
    *(float4*)(out + (size_t)t * HD + h0) = o;
}

// ---------------- launch ----------------
// Workspace aliasing (dependency-audited):
//   part (8 MB)  aliases act    : part written by prep, consumed by topk,
//                                 act written only later by GEMM1.
//   eout (72 MB) aliases xb+wgup_t (74 MB): both dead after GEMM1; eout
//                                 written by GEMM2, read by combine.
// Used workspace: 256 + 8M + 66M + 33M + 36M + ~1.2M ~= 145 MB (was 216).
extern "C" void kernel_launch(void* const* d_in, const int* in_sizes, int n_in,
                              void* d_out, int out_size, void* d_ws, size_t ws_size,
                              hipStream_t stream) {
    const float* x   = (const float*)d_in[0];   // [T,H]
    const float* gw  = (const float*)d_in[1];   // [E,H]
    const float* wgu = (const float*)d_in[2];   // [E,H,2I]
    const float* wdn = (const float*)d_in[3];   // [E,I,H]
    const float* sgu = (const float*)d_in[4];   // [H,2I]
    const float* sdn = (const float*)d_in[5];   // [I,H]
    float* out = (float*)d_out;

    char* w = (char*)d_ws;
    size_t off = 0;
    int* cnt = (int*)(w + off);                       off += 256;
    unsigned short* xb     = (unsigned short*)(w + off); off += (size_t)TT * HD * 2;            // 8 MB
    unsigned short* wgup_t = (unsigned short*)(w + off); off += (size_t)33 * 1024 * 1024 * 2;   // 66 MB
    unsigned short* wdn_t  = (unsigned short*)(w + off); off += (size_t)33 * 1024 * 512 * 2;    // 33 MB
    unsigned short* act    = (unsigned short*)(w + off); off += (size_t)NSLOT * ID * 2;         // 36 MB
    int*   tok    = (int*)(w + off);   off += (size_t)NSLOT * 4;
    float* wgt    = (float*)(w + off); off += (size_t)NSLOT * 4;
    int*   smap   = (int*)(w + off);   off += (size_t)TT * TOPK * 4;
    int*   choice = (int*)(w + off);   off += (size_t)TT * TOPK * 4;
    float* cw     = (float*)(w + off); off += (size_t)TT * TOPK * 4;

    float* part = (float*)act;                        // alias: dead before GEMM1
    unsigned short* eout = xb;                        // alias: xb+wgup_t dead after GEMM1

    // prep: both weight transposes + logits + x->bf16, one launch
    k_prep<<<dim3(16, 16, 67), 256, 0, stream>>>(wgu, sgu, wdn, sdn,
                                                 wgup_t, wdn_t, x, gw, part, xb);
    k_topk<<<TT / 4, 256, 0, stream>>>(part, choice, cw, tok, wgt);
    k_assign<<<NEXP, 1024, 0, stream>>>(choice, cw, cnt, tok, wgt, smap);

    // GEMM1: gathered x @ gate_up^T, fused silu*mul -> act
    k_moe_gemm<1024, true, true><<<dim3(8, MAXTILES), 256, 0, stream>>>(xb, wgup_t, act, tok, cnt);
    // GEMM2: act @ down^T -> eout
    k_moe_gemm<512, false, false><<<dim3(8, MAXTILES), 256, 0, stream>>>(act, wdn_t, eout, tok, cnt);

    k_combine<<<TT, 256, 0, stream>>>(eout, smap, wgt, out);
}